// Round 1
// baseline (5718.042 us; speedup 1.0000x reference)
//
#include <hip/hip_runtime.h>

#define N_NODES 100000
#define EDGES   1600000
#define D       128
#define BN_EPS  1e-5f
#define TM      64      // rows per GEMM block

// ---------------------------------------------------------------------------
// K1: h_pre = (2+eps)*x   (self-loop + (1+eps)x folded);  zero stats[0..255]
// ---------------------------------------------------------------------------
__global__ void init_aggr(const float* __restrict__ x, const float* __restrict__ eps_p,
                          float* __restrict__ aggr, float* __restrict__ stats) {
    long long gid = (long long)blockIdx.x * blockDim.x + threadIdx.x;
    if (gid < 256) stats[gid] = 0.0f;
    const long long n4 = (long long)N_NODES * (D / 4);
    if (gid < n4) {
        const float s = 2.0f + eps_p[0];
        float4 v = ((const float4*)x)[gid];
        v.x *= s; v.y *= s; v.z *= s; v.w *= s;
        ((float4*)aggr)[gid] = v;
    }
}

// ---------------------------------------------------------------------------
// K2: symmetric scatter:  aggr[dst] += x[src]; aggr[src] += x[dst]
// one thread per (edge, float4-chunk); 32 chunks per edge
// ---------------------------------------------------------------------------
__global__ void scatter_edges(const float* __restrict__ x, const int* __restrict__ ei,
                              float* __restrict__ aggr) {
    long long gid = (long long)blockIdx.x * blockDim.x + threadIdx.x;
    int e = (int)(gid >> 5);
    int c = (int)(gid & 31);
    if (e >= EDGES) return;
    int s = ei[e];
    int d = ei[EDGES + e];
    float4 xs = ((const float4*)x)[(long long)s * 32 + c];
    float4 xd = ((const float4*)x)[(long long)d * 32 + c];
    float* ad = aggr + (long long)d * D + c * 4;
    float* as = aggr + (long long)s * D + c * 4;
    atomicAdd(ad + 0, xs.x); atomicAdd(ad + 1, xs.y);
    atomicAdd(ad + 2, xs.z); atomicAdd(ad + 3, xs.w);
    atomicAdd(as + 0, xd.x); atomicAdd(as + 1, xd.y);
    atomicAdd(as + 2, xd.z); atomicAdd(as + 3, xd.w);
}

// ---------------------------------------------------------------------------
// K3: h1 = h_pre @ W1^T + b1  (into d_out as scratch) + BN sum/sumsq stats
// block: 256 threads, tile TM=64 rows x 128 cols, K=128
// thread (tx,ty): cols tx*4..tx*4+3, rows ty*8..ty*8+7
// ---------------------------------------------------------------------------
__launch_bounds__(256)
__global__ void gemm1_stats(const float* __restrict__ hpre, const float* __restrict__ W1,
                            const float* __restrict__ b1, float* __restrict__ h1,
                            float* __restrict__ stats) {
    __shared__ __align__(16) float sA[TM][136];
    __shared__ float sPart[2][8][128];
    const int tid  = threadIdx.x;
    const int tx   = tid & 31;
    const int ty   = tid >> 5;
    const int row0 = blockIdx.x * TM;

    // stage h_pre rows into LDS (coalesced float4)
#pragma unroll
    for (int i = 0; i < 8; ++i) {
        int f = tid + 256 * i;          // [0, 2048)
        int r = f >> 5, c4 = f & 31;
        int gr = row0 + r;
        float4 v = make_float4(0.f, 0.f, 0.f, 0.f);
        if (gr < N_NODES) v = *(const float4*)(hpre + (long long)gr * D + c4 * 4);
        *(float4*)&sA[r][c4 * 4] = v;
    }
    __syncthreads();

    float acc[8][4];
#pragma unroll
    for (int j = 0; j < 8; ++j)
#pragma unroll
        for (int q = 0; q < 4; ++q) acc[j][q] = 0.f;

    const float* w0p = W1 + (tx * 4 + 0) * D;
    const float* w1p = W1 + (tx * 4 + 1) * D;
    const float* w2p = W1 + (tx * 4 + 2) * D;
    const float* w3p = W1 + (tx * 4 + 3) * D;

#pragma unroll 4
    for (int k4 = 0; k4 < 32; ++k4) {
        float4 w0 = *(const float4*)(w0p + k4 * 4);
        float4 w1 = *(const float4*)(w1p + k4 * 4);
        float4 w2 = *(const float4*)(w2p + k4 * 4);
        float4 w3 = *(const float4*)(w3p + k4 * 4);
#pragma unroll
        for (int j = 0; j < 8; ++j) {
            float4 a = *(const float4*)&sA[ty * 8 + j][k4 * 4];
            acc[j][0] = fmaf(a.x, w0.x, fmaf(a.y, w0.y, fmaf(a.z, w0.z, fmaf(a.w, w0.w, acc[j][0]))));
            acc[j][1] = fmaf(a.x, w1.x, fmaf(a.y, w1.y, fmaf(a.z, w1.z, fmaf(a.w, w1.w, acc[j][1]))));
            acc[j][2] = fmaf(a.x, w2.x, fmaf(a.y, w2.y, fmaf(a.z, w2.z, fmaf(a.w, w2.w, acc[j][2]))));
            acc[j][3] = fmaf(a.x, w3.x, fmaf(a.y, w3.y, fmaf(a.z, w3.z, fmaf(a.w, w3.w, acc[j][3]))));
        }
    }

    // epilogue: +b1, write h1, per-thread partial BN stats (valid rows only)
    float4 bb = *(const float4*)(b1 + tx * 4);
    float psum[4] = {0.f, 0.f, 0.f, 0.f};
    float psq[4]  = {0.f, 0.f, 0.f, 0.f};
#pragma unroll
    for (int j = 0; j < 8; ++j) {
        int gr = row0 + ty * 8 + j;
        if (gr < N_NODES) {
            float4 o;
            o.x = acc[j][0] + bb.x;
            o.y = acc[j][1] + bb.y;
            o.z = acc[j][2] + bb.z;
            o.w = acc[j][3] + bb.w;
            *(float4*)(h1 + (long long)gr * D + tx * 4) = o;
            psum[0] += o.x; psum[1] += o.y; psum[2] += o.z; psum[3] += o.w;
            psq[0] += o.x * o.x; psq[1] += o.y * o.y;
            psq[2] += o.z * o.z; psq[3] += o.w * o.w;
        }
    }
#pragma unroll
    for (int q = 0; q < 4; ++q) {
        sPart[0][ty][tx * 4 + q] = psum[q];
        sPart[1][ty][tx * 4 + q] = psq[q];
    }
    __syncthreads();
    if (tid < 128) {
        float s = 0.f, ss = 0.f;
#pragma unroll
        for (int t = 0; t < 8; ++t) { s += sPart[0][t][tid]; ss += sPart[1][t][tid]; }
        atomicAdd(&stats[tid], s);
        atomicAdd(&stats[128 + tid], ss);
    }
}

// ---------------------------------------------------------------------------
// K4: finalize BN: scale = gamma*rsqrt(var+eps), shift = beta - mean*scale
// ---------------------------------------------------------------------------
__global__ void finalize_stats(const float* __restrict__ gamma, const float* __restrict__ beta,
                               float* __restrict__ stats) {
    int c = threadIdx.x;
    float mean = stats[c] * (1.0f / N_NODES);
    float var  = fmaxf(stats[128 + c] * (1.0f / N_NODES) - mean * mean, 0.0f);
    float sc   = gamma[c] * rsqrtf(var + BN_EPS);
    stats[256 + c] = sc;
    stats[384 + c] = beta[c] - mean * sc;
}

// ---------------------------------------------------------------------------
// K5: out = relu(bn(h1)) @ W2^T + b2   -- in-place on d_out (h1 lives there);
// safe: each block reads all K of its exclusive rows into LDS before writing.
// ---------------------------------------------------------------------------
__launch_bounds__(256)
__global__ void bn_relu_gemm2(float* __restrict__ h1out, const float* __restrict__ W2,
                              const float* __restrict__ b2, const float* __restrict__ stats) {
    __shared__ __align__(16) float sA[TM][136];
    const int tid  = threadIdx.x;
    const int tx   = tid & 31;
    const int ty   = tid >> 5;
    const int row0 = blockIdx.x * TM;

#pragma unroll
    for (int i = 0; i < 8; ++i) {
        int f = tid + 256 * i;
        int r = f >> 5, c4 = f & 31;
        int gr = row0 + r;
        float4 v = make_float4(0.f, 0.f, 0.f, 0.f);
        if (gr < N_NODES) {
            v = *(const float4*)(h1out + (long long)gr * D + c4 * 4);
            float4 sc = *(const float4*)(stats + 256 + c4 * 4);
            float4 sh = *(const float4*)(stats + 384 + c4 * 4);
            v.x = fmaxf(0.f, fmaf(v.x, sc.x, sh.x));
            v.y = fmaxf(0.f, fmaf(v.y, sc.y, sh.y));
            v.z = fmaxf(0.f, fmaf(v.z, sc.z, sh.z));
            v.w = fmaxf(0.f, fmaf(v.w, sc.w, sh.w));
        }
        *(float4*)&sA[r][c4 * 4] = v;
    }
    __syncthreads();

    float acc[8][4];
#pragma unroll
    for (int j = 0; j < 8; ++j)
#pragma unroll
        for (int q = 0; q < 4; ++q) acc[j][q] = 0.f;

    const float* w0p = W2 + (tx * 4 + 0) * D;
    const float* w1p = W2 + (tx * 4 + 1) * D;
    const float* w2p = W2 + (tx * 4 + 2) * D;
    const float* w3p = W2 + (tx * 4 + 3) * D;

#pragma unroll 4
    for (int k4 = 0; k4 < 32; ++k4) {
        float4 w0 = *(const float4*)(w0p + k4 * 4);
        float4 w1 = *(const float4*)(w1p + k4 * 4);
        float4 w2 = *(const float4*)(w2p + k4 * 4);
        float4 w3 = *(const float4*)(w3p + k4 * 4);
#pragma unroll
        for (int j = 0; j < 8; ++j) {
            float4 a = *(const float4*)&sA[ty * 8 + j][k4 * 4];
            acc[j][0] = fmaf(a.x, w0.x, fmaf(a.y, w0.y, fmaf(a.z, w0.z, fmaf(a.w, w0.w, acc[j][0]))));
            acc[j][1] = fmaf(a.x, w1.x, fmaf(a.y, w1.y, fmaf(a.z, w1.z, fmaf(a.w, w1.w, acc[j][1]))));
            acc[j][2] = fmaf(a.x, w2.x, fmaf(a.y, w2.y, fmaf(a.z, w2.z, fmaf(a.w, w2.w, acc[j][2]))));
            acc[j][3] = fmaf(a.x, w3.x, fmaf(a.y, w3.y, fmaf(a.z, w3.z, fmaf(a.w, w3.w, acc[j][3]))));
        }
    }

    float4 bb = *(const float4*)(b2 + tx * 4);
#pragma unroll
    for (int j = 0; j < 8; ++j) {
        int gr = row0 + ty * 8 + j;
        if (gr < N_NODES) {
            float4 o;
            o.x = acc[j][0] + bb.x;
            o.y = acc[j][1] + bb.y;
            o.z = acc[j][2] + bb.z;
            o.w = acc[j][3] + bb.w;
            *(float4*)(h1out + (long long)gr * D + tx * 4) = o;
        }
    }
}

// ---------------------------------------------------------------------------
extern "C" void kernel_launch(void* const* d_in, const int* in_sizes, int n_in,
                              void* d_out, int out_size, void* d_ws, size_t ws_size,
                              hipStream_t stream) {
    const float* x     = (const float*)d_in[0];
    const int*   ei    = (const int*)d_in[1];
    const float* eps_p = (const float*)d_in[2];
    const float* W1    = (const float*)d_in[3];
    const float* b1    = (const float*)d_in[4];
    const float* gamma = (const float*)d_in[5];
    const float* beta  = (const float*)d_in[6];
    const float* W2    = (const float*)d_in[7];
    const float* b2    = (const float*)d_in[8];

    float* aggr  = (float*)d_ws;                        // N*128 floats (h_pre)
    float* stats = aggr + (long long)N_NODES * D;       // 512 floats
    float* out   = (float*)d_out;                       // doubles as h1 scratch

    {   // K1: init h_pre = (2+eps)*x, zero stats
        long long n4 = (long long)N_NODES * (D / 4);
        int grid = (int)((n4 + 255) / 256);
        init_aggr<<<grid, 256, 0, stream>>>(x, eps_p, aggr, stats);
    }
    {   // K2: symmetric atomic scatter
        long long t = (long long)EDGES * 32;
        int grid = (int)((t + 255) / 256);
        scatter_edges<<<grid, 256, 0, stream>>>(x, ei, aggr);
    }
    {   // K3: GEMM1 + BN stats (h1 -> d_out)
        int grid = (N_NODES + TM - 1) / TM;
        gemm1_stats<<<grid, 256, 0, stream>>>(aggr, W1, b1, out, stats);
    }
    {   // K4: finalize scale/shift
        finalize_stats<<<1, 128, 0, stream>>>(gamma, beta, stats);
    }
    {   // K5: BN+ReLU+GEMM2, in-place on d_out
        int grid = (N_NODES + TM - 1) / TM;
        bn_relu_gemm2<<<grid, 256, 0, stream>>>(out, W2, b2, stats);
    }
}

// Round 2
// 1350.146 us; speedup vs baseline: 4.2351x; 4.2351x over previous
//
#include <hip/hip_runtime.h>

#define N_NODES 100000
#define EDGES   1600000
#define D       128
#define BN_EPS  1e-5f
#define TM      64      // rows per GEMM block

// ---------------------------------------------------------------------------
// K_hist: degree histogram over augmented (symmetric) edges
// ---------------------------------------------------------------------------
__global__ void histo(const int* __restrict__ ei, int* __restrict__ deg) {
    int e = blockIdx.x * blockDim.x + threadIdx.x;
    if (e >= EDGES) return;
    atomicAdd(&deg[ei[e]], 1);
    atomicAdd(&deg[ei[EDGES + e]], 1);
}

// ---------------------------------------------------------------------------
// K_scan: exclusive prefix sum of deg -> off, cursor (single 1024-thread block)
// ---------------------------------------------------------------------------
__global__ void scan_offsets(const int* __restrict__ deg, int* __restrict__ off,
                             int* __restrict__ cursor) {
    const int T = 1024;
    const int CH = (N_NODES + T - 1) / T;   // 98
    __shared__ int sums[T];
    int t = threadIdx.x;
    int base = t * CH;
    int s = 0;
    for (int i = 0; i < CH; ++i) {
        int idx = base + i;
        if (idx < N_NODES) s += deg[idx];
    }
    sums[t] = s;
    __syncthreads();
    for (int d = 1; d < T; d <<= 1) {
        int v = 0;
        if (t >= d) v = sums[t - d];
        __syncthreads();
        if (t >= d) sums[t] += v;
        __syncthreads();
    }
    int run = (t > 0) ? sums[t - 1] : 0;
    for (int i = 0; i < CH; ++i) {
        int idx = base + i;
        if (idx < N_NODES) {
            off[idx] = run;
            cursor[idx] = run;
            run += deg[idx];
        }
    }
    if (t == T - 1) off[N_NODES] = run;
}

// ---------------------------------------------------------------------------
// K_fill: scatter edge endpoints into CSR buckets
// edge (s,d): d's list gets s, s's list gets d  (handles self-loops: 2 copies)
// ---------------------------------------------------------------------------
__global__ void fill_adj(const int* __restrict__ ei, int* __restrict__ cursor,
                         int* __restrict__ adj) {
    int e = blockIdx.x * blockDim.x + threadIdx.x;
    if (e >= EDGES) return;
    int s = ei[e];
    int d = ei[EDGES + e];
    int p = atomicAdd(&cursor[d], 1);
    adj[p] = s;
    int q = atomicAdd(&cursor[s], 1);
    adj[q] = d;
}

// ---------------------------------------------------------------------------
// K_gather: h_pre[v] = (2+eps)*x[v] + sum_{u in adj(v)} x[u]
// one wave per node; lane handles one float2 column pair (coalesced 512B/row)
// ---------------------------------------------------------------------------
__launch_bounds__(256)
__global__ void gather_aggr(const float* __restrict__ x, const int* __restrict__ adj,
                            const int* __restrict__ off, const float* __restrict__ eps_p,
                            float* __restrict__ hpre) {
    int node = blockIdx.x * 4 + (threadIdx.x >> 6);
    int lane = threadIdx.x & 63;
    if (node >= N_NODES) return;
    int b = off[node];
    int e = off[node + 1];
    const float2* xp = (const float2*)x;
    float2 acc = make_float2(0.f, 0.f);
    for (int i = b; i < e; ++i) {
        int nb = adj[i];                         // wave-uniform -> scalar load
        float2 v = xp[(long long)nb * 64 + lane];
        acc.x += v.x; acc.y += v.y;
    }
    float2 xs = xp[(long long)node * 64 + lane];
    float sc = 2.0f + eps_p[0];
    acc.x = fmaf(sc, xs.x, acc.x);
    acc.y = fmaf(sc, xs.y, acc.y);
    ((float2*)hpre)[(long long)node * 64 + lane] = acc;
}

// ---------------------------------------------------------------------------
// K3: h1 = h_pre @ W1^T + b1  (into d_out as scratch) + BN sum/sumsq stats
// ---------------------------------------------------------------------------
__launch_bounds__(256)
__global__ void gemm1_stats(const float* __restrict__ hpre, const float* __restrict__ W1,
                            const float* __restrict__ b1, float* __restrict__ h1,
                            float* __restrict__ stats) {
    __shared__ __align__(16) float sA[TM][136];
    __shared__ float sPart[2][8][128];
    const int tid  = threadIdx.x;
    const int tx   = tid & 31;
    const int ty   = tid >> 5;
    const int row0 = blockIdx.x * TM;

#pragma unroll
    for (int i = 0; i < 8; ++i) {
        int f = tid + 256 * i;
        int r = f >> 5, c4 = f & 31;
        int gr = row0 + r;
        float4 v = make_float4(0.f, 0.f, 0.f, 0.f);
        if (gr < N_NODES) v = *(const float4*)(hpre + (long long)gr * D + c4 * 4);
        *(float4*)&sA[r][c4 * 4] = v;
    }
    __syncthreads();

    float acc[8][4];
#pragma unroll
    for (int j = 0; j < 8; ++j)
#pragma unroll
        for (int q = 0; q < 4; ++q) acc[j][q] = 0.f;

    const float* w0p = W1 + (tx * 4 + 0) * D;
    const float* w1p = W1 + (tx * 4 + 1) * D;
    const float* w2p = W1 + (tx * 4 + 2) * D;
    const float* w3p = W1 + (tx * 4 + 3) * D;

#pragma unroll 4
    for (int k4 = 0; k4 < 32; ++k4) {
        float4 w0 = *(const float4*)(w0p + k4 * 4);
        float4 w1 = *(const float4*)(w1p + k4 * 4);
        float4 w2 = *(const float4*)(w2p + k4 * 4);
        float4 w3 = *(const float4*)(w3p + k4 * 4);
#pragma unroll
        for (int j = 0; j < 8; ++j) {
            float4 a = *(const float4*)&sA[ty * 8 + j][k4 * 4];
            acc[j][0] = fmaf(a.x, w0.x, fmaf(a.y, w0.y, fmaf(a.z, w0.z, fmaf(a.w, w0.w, acc[j][0]))));
            acc[j][1] = fmaf(a.x, w1.x, fmaf(a.y, w1.y, fmaf(a.z, w1.z, fmaf(a.w, w1.w, acc[j][1]))));
            acc[j][2] = fmaf(a.x, w2.x, fmaf(a.y, w2.y, fmaf(a.z, w2.z, fmaf(a.w, w2.w, acc[j][2]))));
            acc[j][3] = fmaf(a.x, w3.x, fmaf(a.y, w3.y, fmaf(a.z, w3.z, fmaf(a.w, w3.w, acc[j][3]))));
        }
    }

    float4 bb = *(const float4*)(b1 + tx * 4);
    float psum[4] = {0.f, 0.f, 0.f, 0.f};
    float psq[4]  = {0.f, 0.f, 0.f, 0.f};
#pragma unroll
    for (int j = 0; j < 8; ++j) {
        int gr = row0 + ty * 8 + j;
        if (gr < N_NODES) {
            float4 o;
            o.x = acc[j][0] + bb.x;
            o.y = acc[j][1] + bb.y;
            o.z = acc[j][2] + bb.z;
            o.w = acc[j][3] + bb.w;
            *(float4*)(h1 + (long long)gr * D + tx * 4) = o;
            psum[0] += o.x; psum[1] += o.y; psum[2] += o.z; psum[3] += o.w;
            psq[0] += o.x * o.x; psq[1] += o.y * o.y;
            psq[2] += o.z * o.z; psq[3] += o.w * o.w;
        }
    }
#pragma unroll
    for (int q = 0; q < 4; ++q) {
        sPart[0][ty][tx * 4 + q] = psum[q];
        sPart[1][ty][tx * 4 + q] = psq[q];
    }
    __syncthreads();
    if (tid < 128) {
        float s = 0.f, ss = 0.f;
#pragma unroll
        for (int t = 0; t < 8; ++t) { s += sPart[0][t][tid]; ss += sPart[1][t][tid]; }
        atomicAdd(&stats[tid], s);
        atomicAdd(&stats[128 + tid], ss);
    }
}

// ---------------------------------------------------------------------------
// K4: finalize BN: scale = gamma*rsqrt(var+eps), shift = beta - mean*scale
// ---------------------------------------------------------------------------
__global__ void finalize_stats(const float* __restrict__ gamma, const float* __restrict__ beta,
                               float* __restrict__ stats) {
    int c = threadIdx.x;
    float mean = stats[c] * (1.0f / N_NODES);
    float var  = fmaxf(stats[128 + c] * (1.0f / N_NODES) - mean * mean, 0.0f);
    float sc   = gamma[c] * rsqrtf(var + BN_EPS);
    stats[256 + c] = sc;
    stats[384 + c] = beta[c] - mean * sc;
}

// ---------------------------------------------------------------------------
// K5: out = relu(bn(h1)) @ W2^T + b2   -- in-place on d_out
// ---------------------------------------------------------------------------
__launch_bounds__(256)
__global__ void bn_relu_gemm2(float* __restrict__ h1out, const float* __restrict__ W2,
                              const float* __restrict__ b2, const float* __restrict__ stats) {
    __shared__ __align__(16) float sA[TM][136];
    const int tid  = threadIdx.x;
    const int tx   = tid & 31;
    const int ty   = tid >> 5;
    const int row0 = blockIdx.x * TM;

#pragma unroll
    for (int i = 0; i < 8; ++i) {
        int f = tid + 256 * i;
        int r = f >> 5, c4 = f & 31;
        int gr = row0 + r;
        float4 v = make_float4(0.f, 0.f, 0.f, 0.f);
        if (gr < N_NODES) {
            v = *(const float4*)(h1out + (long long)gr * D + c4 * 4);
            float4 sc = *(const float4*)(stats + 256 + c4 * 4);
            float4 sh = *(const float4*)(stats + 384 + c4 * 4);
            v.x = fmaxf(0.f, fmaf(v.x, sc.x, sh.x));
            v.y = fmaxf(0.f, fmaf(v.y, sc.y, sh.y));
            v.z = fmaxf(0.f, fmaf(v.z, sc.z, sh.z));
            v.w = fmaxf(0.f, fmaf(v.w, sc.w, sh.w));
        }
        *(float4*)&sA[r][c4 * 4] = v;
    }
    __syncthreads();

    float acc[8][4];
#pragma unroll
    for (int j = 0; j < 8; ++j)
#pragma unroll
        for (int q = 0; q < 4; ++q) acc[j][q] = 0.f;

    const float* w0p = W2 + (tx * 4 + 0) * D;
    const float* w1p = W2 + (tx * 4 + 1) * D;
    const float* w2p = W2 + (tx * 4 + 2) * D;
    const float* w3p = W2 + (tx * 4 + 3) * D;

#pragma unroll 4
    for (int k4 = 0; k4 < 32; ++k4) {
        float4 w0 = *(const float4*)(w0p + k4 * 4);
        float4 w1 = *(const float4*)(w1p + k4 * 4);
        float4 w2 = *(const float4*)(w2p + k4 * 4);
        float4 w3 = *(const float4*)(w3p + k4 * 4);
#pragma unroll
        for (int j = 0; j < 8; ++j) {
            float4 a = *(const float4*)&sA[ty * 8 + j][k4 * 4];
            acc[j][0] = fmaf(a.x, w0.x, fmaf(a.y, w0.y, fmaf(a.z, w0.z, fmaf(a.w, w0.w, acc[j][0]))));
            acc[j][1] = fmaf(a.x, w1.x, fmaf(a.y, w1.y, fmaf(a.z, w1.z, fmaf(a.w, w1.w, acc[j][1]))));
            acc[j][2] = fmaf(a.x, w2.x, fmaf(a.y, w2.y, fmaf(a.z, w2.z, fmaf(a.w, w2.w, acc[j][2]))));
            acc[j][3] = fmaf(a.x, w3.x, fmaf(a.y, w3.y, fmaf(a.z, w3.z, fmaf(a.w, w3.w, acc[j][3]))));
        }
    }

    float4 bb = *(const float4*)(b2 + tx * 4);
#pragma unroll
    for (int j = 0; j < 8; ++j) {
        int gr = row0 + ty * 8 + j;
        if (gr < N_NODES) {
            float4 o;
            o.x = acc[j][0] + bb.x;
            o.y = acc[j][1] + bb.y;
            o.z = acc[j][2] + bb.z;
            o.w = acc[j][3] + bb.w;
            *(float4*)(h1out + (long long)gr * D + tx * 4) = o;
        }
    }
}

// ---------------------------------------------------------------------------
extern "C" void kernel_launch(void* const* d_in, const int* in_sizes, int n_in,
                              void* d_out, int out_size, void* d_ws, size_t ws_size,
                              hipStream_t stream) {
    const float* x     = (const float*)d_in[0];
    const int*   ei    = (const int*)d_in[1];
    const float* eps_p = (const float*)d_in[2];
    const float* W1    = (const float*)d_in[3];
    const float* b1    = (const float*)d_in[4];
    const float* gamma = (const float*)d_in[5];
    const float* beta  = (const float*)d_in[6];
    const float* W2    = (const float*)d_in[7];
    const float* b2    = (const float*)d_in[8];

    // workspace layout
    float* aggr   = (float*)d_ws;                       // N*128 floats (h_pre)
    float* stats  = aggr + (long long)N_NODES * D;      // 512 floats
    int*   deg    = (int*)(stats + 512);                // N ints   (zeroed w/ stats)
    int*   off    = deg + N_NODES;                      // N+1 ints
    int*   cursor = off + N_NODES + 1;                  // N ints
    int*   adj    = cursor + N_NODES;                   // 2E ints
    float* out    = (float*)d_out;                      // doubles as h1 scratch

    // zero stats(512 floats) + deg(N ints) in one contiguous memset
    hipMemsetAsync(stats, 0, (512 + N_NODES) * sizeof(int), stream);

    {   // degree histogram
        int grid = (EDGES + 255) / 256;
        histo<<<grid, 256, 0, stream>>>(ei, deg);
    }
    {   // prefix sum -> off, cursor
        scan_offsets<<<1, 1024, 0, stream>>>(deg, off, cursor);
    }
    {   // CSR fill
        int grid = (EDGES + 255) / 256;
        fill_adj<<<grid, 256, 0, stream>>>(ei, cursor, adj);
    }
    {   // gather-aggregate: h_pre
        int grid = (N_NODES + 3) / 4;
        gather_aggr<<<grid, 256, 0, stream>>>(x, adj, off, eps_p, aggr);
    }
    {   // GEMM1 + BN stats (h1 -> d_out)
        int grid = (N_NODES + TM - 1) / TM;
        gemm1_stats<<<grid, 256, 0, stream>>>(aggr, W1, b1, out, stats);
    }
    {   // finalize scale/shift
        finalize_stats<<<1, 128, 0, stream>>>(gamma, beta, stats);
    }
    {   // BN+ReLU+GEMM2, in-place on d_out
        int grid = (N_NODES + TM - 1) / TM;
        bn_relu_gemm2<<<grid, 256, 0, stream>>>(out, W2, b2, stats);
    }
}

// Round 3
// 1217.828 us; speedup vs baseline: 4.6953x; 1.1087x over previous
//
#include <hip/hip_runtime.h>
#include <hip/hip_fp16.h>

#define N_NODES 100000
#define EDGES   1600000
#define D       128
#define BN_EPS  1e-5f
#define TM      64      // rows per GEMM block

// ---------------------------------------------------------------------------
// K0: convert x -> fp16 mirror (in d_out scratch); zero stats(512f)+deg(N int)
// ---------------------------------------------------------------------------
__global__ void convert_zero(const float* __restrict__ x, __half* __restrict__ xh,
                             int* __restrict__ zbase /* stats..deg contiguous */) {
    int gid = blockIdx.x * blockDim.x + threadIdx.x;
    if (gid < 512 + N_NODES) zbase[gid] = 0;
    const int n4 = N_NODES * (D / 4);          // 3.2M float4 chunks
    if (gid < n4) {
        float4 v = ((const float4*)x)[gid];
        __half2 h0 = __float22half2_rn(make_float2(v.x, v.y));
        __half2 h1 = __float22half2_rn(make_float2(v.z, v.w));
        ((__half2*)xh)[(long long)gid * 2 + 0] = h0;
        ((__half2*)xh)[(long long)gid * 2 + 1] = h1;
    }
}

// ---------------------------------------------------------------------------
// K1: degree histogram over augmented (symmetric) edges
// ---------------------------------------------------------------------------
__global__ void histo(const int* __restrict__ ei, int* __restrict__ deg) {
    int e = blockIdx.x * blockDim.x + threadIdx.x;
    if (e >= EDGES) return;
    atomicAdd(&deg[ei[e]], 1);
    atomicAdd(&deg[ei[EDGES + e]], 1);
}

// ---------------------------------------------------------------------------
// K2: exclusive prefix sum of deg -> off, cursor (single 1024-thread block)
// ---------------------------------------------------------------------------
__global__ void scan_offsets(const int* __restrict__ deg, int* __restrict__ off,
                             int* __restrict__ cursor) {
    const int T = 1024;
    const int CH = (N_NODES + T - 1) / T;   // 98
    __shared__ int sums[T];
    int t = threadIdx.x;
    int base = t * CH;
    int s = 0;
    for (int i = 0; i < CH; ++i) {
        int idx = base + i;
        if (idx < N_NODES) s += deg[idx];
    }
    sums[t] = s;
    __syncthreads();
    for (int d = 1; d < T; d <<= 1) {
        int v = 0;
        if (t >= d) v = sums[t - d];
        __syncthreads();
        if (t >= d) sums[t] += v;
        __syncthreads();
    }
    int run = (t > 0) ? sums[t - 1] : 0;
    for (int i = 0; i < CH; ++i) {
        int idx = base + i;
        if (idx < N_NODES) {
            off[idx] = run;
            cursor[idx] = run;
            run += deg[idx];
        }
    }
    if (t == T - 1) off[N_NODES] = run;
}

// ---------------------------------------------------------------------------
// K3: scatter edge endpoints into CSR buckets
// ---------------------------------------------------------------------------
__global__ void fill_adj(const int* __restrict__ ei, int* __restrict__ cursor,
                         int* __restrict__ adj) {
    int e = blockIdx.x * blockDim.x + threadIdx.x;
    if (e >= EDGES) return;
    int s = ei[e];
    int d = ei[EDGES + e];
    int p = atomicAdd(&cursor[d], 1);
    adj[p] = s;
    int q = atomicAdd(&cursor[s], 1);
    adj[q] = d;
}

// ---------------------------------------------------------------------------
// K4: h_pre[v] = (2+eps)*x[v](fp32) + sum_{u in adj(v)} xh[u](fp16)
// one wave per node; lane = one half2 column pair (coalesced 256B/row)
// ---------------------------------------------------------------------------
__launch_bounds__(256)
__global__ void gather_aggr(const float* __restrict__ x, const __half* __restrict__ xh,
                            const int* __restrict__ adj, const int* __restrict__ off,
                            const float* __restrict__ eps_p, float* __restrict__ hpre) {
    int node = blockIdx.x * 4 + (threadIdx.x >> 6);
    int lane = threadIdx.x & 63;
    if (node >= N_NODES) return;
    int b = off[node];
    int e = off[node + 1];
    const __half2* xp = (const __half2*)xh;
    float ax = 0.f, ay = 0.f;
    int i = b;
    for (; i + 2 <= e; i += 2) {               // 2-way unroll: independent loads
        int n0 = adj[i];
        int n1 = adj[i + 1];
        __half2 v0 = xp[(long long)n0 * 64 + lane];
        __half2 v1 = xp[(long long)n1 * 64 + lane];
        float2 f0 = __half22float2(v0);
        float2 f1 = __half22float2(v1);
        ax += f0.x + f1.x;
        ay += f0.y + f1.y;
    }
    if (i < e) {
        __half2 v = xp[(long long)adj[i] * 64 + lane];
        float2 f = __half22float2(v);
        ax += f.x;
        ay += f.y;
    }
    float2 xs = ((const float2*)x)[(long long)node * 64 + lane];
    float sc = 2.0f + eps_p[0];
    float2 o;
    o.x = fmaf(sc, xs.x, ax);
    o.y = fmaf(sc, xs.y, ay);
    ((float2*)hpre)[(long long)node * 64 + lane] = o;
}

// ---------------------------------------------------------------------------
// K5: h1 = h_pre @ W1^T + b1  (into d_out) + BN sum/sumsq stats
// ---------------------------------------------------------------------------
__launch_bounds__(256)
__global__ void gemm1_stats(const float* __restrict__ hpre, const float* __restrict__ W1,
                            const float* __restrict__ b1, float* __restrict__ h1,
                            float* __restrict__ stats) {
    __shared__ __align__(16) float sA[TM][136];
    __shared__ float sPart[2][8][128];
    const int tid  = threadIdx.x;
    const int tx   = tid & 31;
    const int ty   = tid >> 5;
    const int row0 = blockIdx.x * TM;

#pragma unroll
    for (int i = 0; i < 8; ++i) {
        int f = tid + 256 * i;
        int r = f >> 5, c4 = f & 31;
        int gr = row0 + r;
        float4 v = make_float4(0.f, 0.f, 0.f, 0.f);
        if (gr < N_NODES) v = *(const float4*)(hpre + (long long)gr * D + c4 * 4);
        *(float4*)&sA[r][c4 * 4] = v;
    }
    __syncthreads();

    float acc[8][4];
#pragma unroll
    for (int j = 0; j < 8; ++j)
#pragma unroll
        for (int q = 0; q < 4; ++q) acc[j][q] = 0.f;

    const float* w0p = W1 + (tx * 4 + 0) * D;
    const float* w1p = W1 + (tx * 4 + 1) * D;
    const float* w2p = W1 + (tx * 4 + 2) * D;
    const float* w3p = W1 + (tx * 4 + 3) * D;

#pragma unroll 4
    for (int k4 = 0; k4 < 32; ++k4) {
        float4 w0 = *(const float4*)(w0p + k4 * 4);
        float4 w1 = *(const float4*)(w1p + k4 * 4);
        float4 w2 = *(const float4*)(w2p + k4 * 4);
        float4 w3 = *(const float4*)(w3p + k4 * 4);
#pragma unroll
        for (int j = 0; j < 8; ++j) {
            float4 a = *(const float4*)&sA[ty * 8 + j][k4 * 4];
            acc[j][0] = fmaf(a.x, w0.x, fmaf(a.y, w0.y, fmaf(a.z, w0.z, fmaf(a.w, w0.w, acc[j][0]))));
            acc[j][1] = fmaf(a.x, w1.x, fmaf(a.y, w1.y, fmaf(a.z, w1.z, fmaf(a.w, w1.w, acc[j][1]))));
            acc[j][2] = fmaf(a.x, w2.x, fmaf(a.y, w2.y, fmaf(a.z, w2.z, fmaf(a.w, w2.w, acc[j][2]))));
            acc[j][3] = fmaf(a.x, w3.x, fmaf(a.y, w3.y, fmaf(a.z, w3.z, fmaf(a.w, w3.w, acc[j][3]))));
        }
    }

    float4 bb = *(const float4*)(b1 + tx * 4);
    float psum[4] = {0.f, 0.f, 0.f, 0.f};
    float psq[4]  = {0.f, 0.f, 0.f, 0.f};
#pragma unroll
    for (int j = 0; j < 8; ++j) {
        int gr = row0 + ty * 8 + j;
        if (gr < N_NODES) {
            float4 o;
            o.x = acc[j][0] + bb.x;
            o.y = acc[j][1] + bb.y;
            o.z = acc[j][2] + bb.z;
            o.w = acc[j][3] + bb.w;
            *(float4*)(h1 + (long long)gr * D + tx * 4) = o;
            psum[0] += o.x; psum[1] += o.y; psum[2] += o.z; psum[3] += o.w;
            psq[0] += o.x * o.x; psq[1] += o.y * o.y;
            psq[2] += o.z * o.z; psq[3] += o.w * o.w;
        }
    }
#pragma unroll
    for (int q = 0; q < 4; ++q) {
        sPart[0][ty][tx * 4 + q] = psum[q];
        sPart[1][ty][tx * 4 + q] = psq[q];
    }
    __syncthreads();
    if (tid < 128) {
        float s = 0.f, ss = 0.f;
#pragma unroll
        for (int t = 0; t < 8; ++t) { s += sPart[0][t][tid]; ss += sPart[1][t][tid]; }
        atomicAdd(&stats[tid], s);
        atomicAdd(&stats[128 + tid], ss);
    }
}

// ---------------------------------------------------------------------------
// K6: out = relu(bn(h1)) @ W2^T + b2  -- in-place on d_out; BN finalize fused
// ---------------------------------------------------------------------------
__launch_bounds__(256)
__global__ void bn_relu_gemm2(float* __restrict__ h1out, const float* __restrict__ W2,
                              const float* __restrict__ b2, const float* __restrict__ stats,
                              const float* __restrict__ gamma, const float* __restrict__ beta) {
    __shared__ __align__(16) float sA[TM][136];
    __shared__ __align__(16) float sScale[128];
    __shared__ __align__(16) float sShift[128];
    const int tid  = threadIdx.x;
    const int tx   = tid & 31;
    const int ty   = tid >> 5;
    const int row0 = blockIdx.x * TM;

    if (tid < 128) {                       // fused BN finalize (per block, cheap)
        float mean = stats[tid] * (1.0f / N_NODES);
        float var  = fmaxf(stats[128 + tid] * (1.0f / N_NODES) - mean * mean, 0.0f);
        float s    = gamma[tid] * rsqrtf(var + BN_EPS);
        sScale[tid] = s;
        sShift[tid] = beta[tid] - mean * s;
    }
    __syncthreads();

#pragma unroll
    for (int i = 0; i < 8; ++i) {
        int f = tid + 256 * i;
        int r = f >> 5, c4 = f & 31;
        int gr = row0 + r;
        float4 v = make_float4(0.f, 0.f, 0.f, 0.f);
        if (gr < N_NODES) {
            v = *(const float4*)(h1out + (long long)gr * D + c4 * 4);
            float4 sc = *(const float4*)&sScale[c4 * 4];
            float4 sh = *(const float4*)&sShift[c4 * 4];
            v.x = fmaxf(0.f, fmaf(v.x, sc.x, sh.x));
            v.y = fmaxf(0.f, fmaf(v.y, sc.y, sh.y));
            v.z = fmaxf(0.f, fmaf(v.z, sc.z, sh.z));
            v.w = fmaxf(0.f, fmaf(v.w, sc.w, sh.w));
        }
        *(float4*)&sA[r][c4 * 4] = v;
    }
    __syncthreads();

    float acc[8][4];
#pragma unroll
    for (int j = 0; j < 8; ++j)
#pragma unroll
        for (int q = 0; q < 4; ++q) acc[j][q] = 0.f;

    const float* w0p = W2 + (tx * 4 + 0) * D;
    const float* w1p = W2 + (tx * 4 + 1) * D;
    const float* w2p = W2 + (tx * 4 + 2) * D;
    const float* w3p = W2 + (tx * 4 + 3) * D;

#pragma unroll 4
    for (int k4 = 0; k4 < 32; ++k4) {
        float4 w0 = *(const float4*)(w0p + k4 * 4);
        float4 w1 = *(const float4*)(w1p + k4 * 4);
        float4 w2 = *(const float4*)(w2p + k4 * 4);
        float4 w3 = *(const float4*)(w3p + k4 * 4);
#pragma unroll
        for (int j = 0; j < 8; ++j) {
            float4 a = *(const float4*)&sA[ty * 8 + j][k4 * 4];
            acc[j][0] = fmaf(a.x, w0.x, fmaf(a.y, w0.y, fmaf(a.z, w0.z, fmaf(a.w, w0.w, acc[j][0]))));
            acc[j][1] = fmaf(a.x, w1.x, fmaf(a.y, w1.y, fmaf(a.z, w1.z, fmaf(a.w, w1.w, acc[j][1]))));
            acc[j][2] = fmaf(a.x, w2.x, fmaf(a.y, w2.y, fmaf(a.z, w2.z, fmaf(a.w, w2.w, acc[j][2]))));
            acc[j][3] = fmaf(a.x, w3.x, fmaf(a.y, w3.y, fmaf(a.z, w3.z, fmaf(a.w, w3.w, acc[j][3]))));
        }
    }

    float4 bb = *(const float4*)(b2 + tx * 4);
#pragma unroll
    for (int j = 0; j < 8; ++j) {
        int gr = row0 + ty * 8 + j;
        if (gr < N_NODES) {
            float4 o;
            o.x = acc[j][0] + bb.x;
            o.y = acc[j][1] + bb.y;
            o.z = acc[j][2] + bb.z;
            o.w = acc[j][3] + bb.w;
            *(float4*)(h1out + (long long)gr * D + tx * 4) = o;
        }
    }
}

// ---------------------------------------------------------------------------
extern "C" void kernel_launch(void* const* d_in, const int* in_sizes, int n_in,
                              void* d_out, int out_size, void* d_ws, size_t ws_size,
                              hipStream_t stream) {
    const float* x     = (const float*)d_in[0];
    const int*   ei    = (const int*)d_in[1];
    const float* eps_p = (const float*)d_in[2];
    const float* W1    = (const float*)d_in[3];
    const float* b1    = (const float*)d_in[4];
    const float* gamma = (const float*)d_in[5];
    const float* beta  = (const float*)d_in[6];
    const float* W2    = (const float*)d_in[7];
    const float* b2    = (const float*)d_in[8];

    // workspace layout (same footprint as R2: ~65 MB)
    float* aggr   = (float*)d_ws;                       // N*128 floats (h_pre)
    float* stats  = aggr + (long long)N_NODES * D;      // 512 floats
    int*   deg    = (int*)(stats + 512);                // N ints (contiguous after stats)
    int*   off    = deg + N_NODES;                      // N+1 ints
    int*   cursor = off + N_NODES + 1;                  // N ints
    int*   adj    = cursor + N_NODES;                   // 2E ints
    float* out    = (float*)d_out;                      // h1 scratch + final out
    __half* xh    = (__half*)d_out;                     // fp16 mirror (dead after gather)

    {   // K0: fp16 convert + zero stats/deg
        int grid = (N_NODES * (D / 4) + 255) / 256;
        convert_zero<<<grid, 256, 0, stream>>>(x, xh, (int*)stats);
    }
    {   // K1: degree histogram
        int grid = (EDGES + 255) / 256;
        histo<<<grid, 256, 0, stream>>>(ei, deg);
    }
    {   // K2: prefix sum -> off, cursor
        scan_offsets<<<1, 1024, 0, stream>>>(deg, off, cursor);
    }
    {   // K3: CSR fill
        int grid = (EDGES + 255) / 256;
        fill_adj<<<grid, 256, 0, stream>>>(ei, cursor, adj);
    }
    {   // K4: gather-aggregate (fp16 neighbor reads, fp32 self term)
        int grid = (N_NODES + 3) / 4;
        gather_aggr<<<grid, 256, 0, stream>>>(x, xh, adj, off, eps_p, aggr);
    }
    {   // K5: GEMM1 + BN stats (h1 -> d_out, overwrites xh)
        int grid = (N_NODES + TM - 1) / TM;
        gemm1_stats<<<grid, 256, 0, stream>>>(aggr, W1, b1, out, stats);
    }
    {   // K6: BN finalize + ReLU + GEMM2, in-place on d_out
        int grid = (N_NODES + TM - 1) / TM;
        bn_relu_gemm2<<<grid, 256, 0, stream>>>(out, W2, b2, stats, gamma, beta);
    }
}

// Round 4
// 1172.251 us; speedup vs baseline: 4.8778x; 1.0389x over previous
//
#include <hip/hip_runtime.h>
#include <hip/hip_fp16.h>

#define N_NODES 100000
#define EDGES   1600000
#define D       128
#define BN_EPS  1e-5f
#define TM      64      // rows per GEMM block

// ---------------------------------------------------------------------------
// K0: convert x -> fp16 mirror (in d_out scratch); zero stats(512f)+deg(N int)
// ---------------------------------------------------------------------------
__global__ void convert_zero(const float* __restrict__ x, __half* __restrict__ xh,
                             int* __restrict__ zbase /* stats..deg contiguous */) {
    int gid = blockIdx.x * blockDim.x + threadIdx.x;
    if (gid < 512 + N_NODES) zbase[gid] = 0;
    const int n4 = N_NODES * (D / 4);          // 3.2M float4 chunks
    if (gid < n4) {
        float4 v = ((const float4*)x)[gid];
        __half2 h0 = __float22half2_rn(make_float2(v.x, v.y));
        __half2 h1 = __float22half2_rn(make_float2(v.z, v.w));
        ((__half2*)xh)[(long long)gid * 2 + 0] = h0;
        ((__half2*)xh)[(long long)gid * 2 + 1] = h1;
    }
}

// ---------------------------------------------------------------------------
// K1: degree histogram, 4 edges/thread (no-return atomics pipeline freely)
// ---------------------------------------------------------------------------
#define HB 4
__global__ void histo(const int* __restrict__ ei, int* __restrict__ deg) {
    const int S = EDGES / HB;                  // 400000
    int i = blockIdx.x * blockDim.x + threadIdx.x;
    if (i >= S) return;
    int s[HB], d[HB];
#pragma unroll
    for (int j = 0; j < HB; ++j) {
        s[j] = ei[i + j * S];
        d[j] = ei[EDGES + i + j * S];
    }
#pragma unroll
    for (int j = 0; j < HB; ++j) atomicAdd(&deg[s[j]], 1);
#pragma unroll
    for (int j = 0; j < HB; ++j) atomicAdd(&deg[d[j]], 1);
}

// ---------------------------------------------------------------------------
// K2: exclusive prefix sum of deg -> off, cursor (single 1024-thread block)
// ---------------------------------------------------------------------------
__global__ void scan_offsets(const int* __restrict__ deg, int* __restrict__ off,
                             int* __restrict__ cursor) {
    const int T = 1024;
    const int CH = (N_NODES + T - 1) / T;   // 98
    __shared__ int sums[T];
    int t = threadIdx.x;
    int base = t * CH;
    int s = 0;
    for (int i = 0; i < CH; ++i) {
        int idx = base + i;
        if (idx < N_NODES) s += deg[idx];
    }
    sums[t] = s;
    __syncthreads();
    for (int d = 1; d < T; d <<= 1) {
        int v = 0;
        if (t >= d) v = sums[t - d];
        __syncthreads();
        if (t >= d) sums[t] += v;
        __syncthreads();
    }
    int run = (t > 0) ? sums[t - 1] : 0;
    for (int i = 0; i < CH; ++i) {
        int idx = base + i;
        if (idx < N_NODES) {
            off[idx] = run;
            cursor[idx] = run;
            run += deg[idx];
        }
    }
    if (t == T - 1) off[N_NODES] = run;
}

// ---------------------------------------------------------------------------
// K3: CSR fill, 8 endpoint-slots per thread for atomic MLP.
// slot t in [0,2E): val = ei[t]; node = ei[t<E ? t+E : t-E]
//  (t<E: edge t into dst's list; t>=E: edge t-E into src's list)
// ---------------------------------------------------------------------------
#define FB 8
__global__ void fill_adj(const int* __restrict__ ei, int* __restrict__ cursor,
                         int* __restrict__ adj) {
    const int S = (2 * EDGES) / FB;            // 400000
    int i = blockIdx.x * blockDim.x + threadIdx.x;
    if (i >= S) return;
    int node[FB], val[FB], pos[FB];
#pragma unroll
    for (int j = 0; j < FB; ++j) {
        int t = i + j * S;
        val[j] = ei[t];
        int pt = (t < EDGES) ? t + EDGES : t - EDGES;
        node[j] = ei[pt];
    }
#pragma unroll
    for (int j = 0; j < FB; ++j) pos[j] = atomicAdd(&cursor[node[j]], 1);
#pragma unroll
    for (int j = 0; j < FB; ++j) adj[pos[j]] = val[j];
}

// ---------------------------------------------------------------------------
// K4: h_pre[v] = (2+eps)*x[v](fp32) + sum_{u in adj(v)} xh[u](fp16)
// one wave per node; lane = one half2 pair; 4 outstanding row reads
// ---------------------------------------------------------------------------
__launch_bounds__(256)
__global__ void gather_aggr(const float* __restrict__ x, const __half* __restrict__ xh,
                            const int* __restrict__ adj, const int* __restrict__ off,
                            const float* __restrict__ eps_p, float* __restrict__ hpre) {
    int node = blockIdx.x * 4 + (threadIdx.x >> 6);
    int lane = threadIdx.x & 63;
    if (node >= N_NODES) return;
    int b = off[node];
    int e = off[node + 1];
    const __half2* xp = (const __half2*)xh;
    float ax = 0.f, ay = 0.f;
    int i = b;
    for (; i + 4 <= e; i += 4) {               // 4 independent 256B row reads
        int n0 = adj[i], n1 = adj[i + 1], n2 = adj[i + 2], n3 = adj[i + 3];
        __half2 v0 = xp[(long long)n0 * 64 + lane];
        __half2 v1 = xp[(long long)n1 * 64 + lane];
        __half2 v2 = xp[(long long)n2 * 64 + lane];
        __half2 v3 = xp[(long long)n3 * 64 + lane];
        float2 f0 = __half22float2(v0);
        float2 f1 = __half22float2(v1);
        float2 f2 = __half22float2(v2);
        float2 f3 = __half22float2(v3);
        ax += (f0.x + f1.x) + (f2.x + f3.x);
        ay += (f0.y + f1.y) + (f2.y + f3.y);
    }
    for (; i < e; ++i) {
        __half2 v = xp[(long long)adj[i] * 64 + lane];
        float2 f = __half22float2(v);
        ax += f.x;
        ay += f.y;
    }
    float2 xs = ((const float2*)x)[(long long)node * 64 + lane];
    float sc = 2.0f + eps_p[0];
    float2 o;
    o.x = fmaf(sc, xs.x, ax);
    o.y = fmaf(sc, xs.y, ay);
    ((float2*)hpre)[(long long)node * 64 + lane] = o;
}

// ---------------------------------------------------------------------------
// K5: h1 = h_pre @ W1^T + b1  (into d_out) + BN sum/sumsq stats
// ---------------------------------------------------------------------------
__launch_bounds__(256)
__global__ void gemm1_stats(const float* __restrict__ hpre, const float* __restrict__ W1,
                            const float* __restrict__ b1, float* __restrict__ h1,
                            float* __restrict__ stats) {
    __shared__ __align__(16) float sA[TM][136];
    __shared__ float sPart[2][8][128];
    const int tid  = threadIdx.x;
    const int tx   = tid & 31;
    const int ty   = tid >> 5;
    const int row0 = blockIdx.x * TM;

#pragma unroll
    for (int i = 0; i < 8; ++i) {
        int f = tid + 256 * i;
        int r = f >> 5, c4 = f & 31;
        int gr = row0 + r;
        float4 v = make_float4(0.f, 0.f, 0.f, 0.f);
        if (gr < N_NODES) v = *(const float4*)(hpre + (long long)gr * D + c4 * 4);
        *(float4*)&sA[r][c4 * 4] = v;
    }
    __syncthreads();

    float acc[8][4];
#pragma unroll
    for (int j = 0; j < 8; ++j)
#pragma unroll
        for (int q = 0; q < 4; ++q) acc[j][q] = 0.f;

    const float* w0p = W1 + (tx * 4 + 0) * D;
    const float* w1p = W1 + (tx * 4 + 1) * D;
    const float* w2p = W1 + (tx * 4 + 2) * D;
    const float* w3p = W1 + (tx * 4 + 3) * D;

#pragma unroll 4
    for (int k4 = 0; k4 < 32; ++k4) {
        float4 w0 = *(const float4*)(w0p + k4 * 4);
        float4 w1 = *(const float4*)(w1p + k4 * 4);
        float4 w2 = *(const float4*)(w2p + k4 * 4);
        float4 w3 = *(const float4*)(w3p + k4 * 4);
#pragma unroll
        for (int j = 0; j < 8; ++j) {
            float4 a = *(const float4*)&sA[ty * 8 + j][k4 * 4];
            acc[j][0] = fmaf(a.x, w0.x, fmaf(a.y, w0.y, fmaf(a.z, w0.z, fmaf(a.w, w0.w, acc[j][0]))));
            acc[j][1] = fmaf(a.x, w1.x, fmaf(a.y, w1.y, fmaf(a.z, w1.z, fmaf(a.w, w1.w, acc[j][1]))));
            acc[j][2] = fmaf(a.x, w2.x, fmaf(a.y, w2.y, fmaf(a.z, w2.z, fmaf(a.w, w2.w, acc[j][2]))));
            acc[j][3] = fmaf(a.x, w3.x, fmaf(a.y, w3.y, fmaf(a.z, w3.z, fmaf(a.w, w3.w, acc[j][3]))));
        }
    }

    float4 bb = *(const float4*)(b1 + tx * 4);
    float psum[4] = {0.f, 0.f, 0.f, 0.f};
    float psq[4]  = {0.f, 0.f, 0.f, 0.f};
#pragma unroll
    for (int j = 0; j < 8; ++j) {
        int gr = row0 + ty * 8 + j;
        if (gr < N_NODES) {
            float4 o;
            o.x = acc[j][0] + bb.x;
            o.y = acc[j][1] + bb.y;
            o.z = acc[j][2] + bb.z;
            o.w = acc[j][3] + bb.w;
            *(float4*)(h1 + (long long)gr * D + tx * 4) = o;
            psum[0] += o.x; psum[1] += o.y; psum[2] += o.z; psum[3] += o.w;
            psq[0] += o.x * o.x; psq[1] += o.y * o.y;
            psq[2] += o.z * o.z; psq[3] += o.w * o.w;
        }
    }
#pragma unroll
    for (int q = 0; q < 4; ++q) {
        sPart[0][ty][tx * 4 + q] = psum[q];
        sPart[1][ty][tx * 4 + q] = psq[q];
    }
    __syncthreads();
    if (tid < 128) {
        float s = 0.f, ss = 0.f;
#pragma unroll
        for (int t = 0; t < 8; ++t) { s += sPart[0][t][tid]; ss += sPart[1][t][tid]; }
        atomicAdd(&stats[tid], s);
        atomicAdd(&stats[128 + tid], ss);
    }
}

// ---------------------------------------------------------------------------
// K6: out = relu(bn(h1)) @ W2^T + b2  -- in-place on d_out; BN finalize fused
// ---------------------------------------------------------------------------
__launch_bounds__(256)
__global__ void bn_relu_gemm2(float* __restrict__ h1out, const float* __restrict__ W2,
                              const float* __restrict__ b2, const float* __restrict__ stats,
                              const float* __restrict__ gamma, const float* __restrict__ beta) {
    __shared__ __align__(16) float sA[TM][136];
    __shared__ __align__(16) float sScale[128];
    __shared__ __align__(16) float sShift[128];
    const int tid  = threadIdx.x;
    const int tx   = tid & 31;
    const int ty   = tid >> 5;
    const int row0 = blockIdx.x * TM;

    if (tid < 128) {
        float mean = stats[tid] * (1.0f / N_NODES);
        float var  = fmaxf(stats[128 + tid] * (1.0f / N_NODES) - mean * mean, 0.0f);
        float s    = gamma[tid] * rsqrtf(var + BN_EPS);
        sScale[tid] = s;
        sShift[tid] = beta[tid] - mean * s;
    }
    __syncthreads();

#pragma unroll
    for (int i = 0; i < 8; ++i) {
        int f = tid + 256 * i;
        int r = f >> 5, c4 = f & 31;
        int gr = row0 + r;
        float4 v = make_float4(0.f, 0.f, 0.f, 0.f);
        if (gr < N_NODES) {
            v = *(const float4*)(h1out + (long long)gr * D + c4 * 4);
            float4 sc = *(const float4*)&sScale[c4 * 4];
            float4 sh = *(const float4*)&sShift[c4 * 4];
            v.x = fmaxf(0.f, fmaf(v.x, sc.x, sh.x));
            v.y = fmaxf(0.f, fmaf(v.y, sc.y, sh.y));
            v.z = fmaxf(0.f, fmaf(v.z, sc.z, sh.z));
            v.w = fmaxf(0.f, fmaf(v.w, sc.w, sh.w));
        }
        *(float4*)&sA[r][c4 * 4] = v;
    }
    __syncthreads();

    float acc[8][4];
#pragma unroll
    for (int j = 0; j < 8; ++j)
#pragma unroll
        for (int q = 0; q < 4; ++q) acc[j][q] = 0.f;

    const float* w0p = W2 + (tx * 4 + 0) * D;
    const float* w1p = W2 + (tx * 4 + 1) * D;
    const float* w2p = W2 + (tx * 4 + 2) * D;
    const float* w3p = W2 + (tx * 4 + 3) * D;

#pragma unroll 4
    for (int k4 = 0; k4 < 32; ++k4) {
        float4 w0 = *(const float4*)(w0p + k4 * 4);
        float4 w1 = *(const float4*)(w1p + k4 * 4);
        float4 w2 = *(const float4*)(w2p + k4 * 4);
        float4 w3 = *(const float4*)(w3p + k4 * 4);
#pragma unroll
        for (int j = 0; j < 8; ++j) {
            float4 a = *(const float4*)&sA[ty * 8 + j][k4 * 4];
            acc[j][0] = fmaf(a.x, w0.x, fmaf(a.y, w0.y, fmaf(a.z, w0.z, fmaf(a.w, w0.w, acc[j][0]))));
            acc[j][1] = fmaf(a.x, w1.x, fmaf(a.y, w1.y, fmaf(a.z, w1.z, fmaf(a.w, w1.w, acc[j][1]))));
            acc[j][2] = fmaf(a.x, w2.x, fmaf(a.y, w2.y, fmaf(a.z, w2.z, fmaf(a.w, w2.w, acc[j][2]))));
            acc[j][3] = fmaf(a.x, w3.x, fmaf(a.y, w3.y, fmaf(a.z, w3.z, fmaf(a.w, w3.w, acc[j][3]))));
        }
    }

    float4 bb = *(const float4*)(b2 + tx * 4);
#pragma unroll
    for (int j = 0; j < 8; ++j) {
        int gr = row0 + ty * 8 + j;
        if (gr < N_NODES) {
            float4 o;
            o.x = acc[j][0] + bb.x;
            o.y = acc[j][1] + bb.y;
            o.z = acc[j][2] + bb.z;
            o.w = acc[j][3] + bb.w;
            *(float4*)(h1out + (long long)gr * D + tx * 4) = o;
        }
    }
}

// ---------------------------------------------------------------------------
extern "C" void kernel_launch(void* const* d_in, const int* in_sizes, int n_in,
                              void* d_out, int out_size, void* d_ws, size_t ws_size,
                              hipStream_t stream) {
    const float* x     = (const float*)d_in[0];
    const int*   ei    = (const int*)d_in[1];
    const float* eps_p = (const float*)d_in[2];
    const float* W1    = (const float*)d_in[3];
    const float* b1    = (const float*)d_in[4];
    const float* gamma = (const float*)d_in[5];
    const float* beta  = (const float*)d_in[6];
    const float* W2    = (const float*)d_in[7];
    const float* b2    = (const float*)d_in[8];

    // workspace layout
    float* aggr   = (float*)d_ws;                       // N*128 floats (h_pre)
    float* stats  = aggr + (long long)N_NODES * D;      // 512 floats
    int*   deg    = (int*)(stats + 512);                // N ints
    int*   off    = deg + N_NODES;                      // N+1 ints
    int*   cursor = off + N_NODES + 1;                  // N ints
    int*   adj    = cursor + N_NODES;                   // 2E ints
    float* out    = (float*)d_out;                      // h1 scratch + final out
    __half* xh    = (__half*)d_out;                     // fp16 mirror (dead after gather)

    {   // K0: fp16 convert + zero stats/deg
        int grid = (N_NODES * (D / 4) + 255) / 256;
        convert_zero<<<grid, 256, 0, stream>>>(x, xh, (int*)stats);
    }
    {   // K1: degree histogram (4 edges/thread)
        int grid = (EDGES / HB + 255) / 256;
        histo<<<grid, 256, 0, stream>>>(ei, deg);
    }
    {   // K2: prefix sum -> off, cursor
        scan_offsets<<<1, 1024, 0, stream>>>(deg, off, cursor);
    }
    {   // K3: CSR fill (8 slots/thread, batched atomics)
        int grid = ((2 * EDGES) / FB + 255) / 256;
        fill_adj<<<grid, 256, 0, stream>>>(ei, cursor, adj);
    }
    {   // K4: gather-aggregate (fp16 neighbor reads, 4-deep MLP)
        int grid = (N_NODES + 3) / 4;
        gather_aggr<<<grid, 256, 0, stream>>>(x, xh, adj, off, eps_p, aggr);
    }
    {   // K5: GEMM1 + BN stats (h1 -> d_out, overwrites xh)
        int grid = (N_NODES + TM - 1) / TM;
        gemm1_stats<<<grid, 256, 0, stream>>>(aggr, W1, b1, out, stats);
    }
    {   // K6: BN finalize + ReLU + GEMM2, in-place on d_out
        int grid = (N_NODES + TM - 1) / TM;
        bn_relu_gemm2<<<grid, 256, 0, stream>>>(out, W2, b2, stats, gamma, beta);
    }
}

// Round 5
// 906.239 us; speedup vs baseline: 6.3096x; 1.2935x over previous
//
#include <hip/hip_runtime.h>
#include <hip/hip_fp16.h>

#define N_NODES 100000
#define EDGES   1600000
#define D       128
#define BN_EPS  1e-5f
#define TM      64                        // rows per GEMM block
#define NB      ((N_NODES + 255) >> 8)    // 391 coarse buckets (256 nodes each)
#define L1E     16                        // slots per thread in partition pass
#define L1TILE  (256 * L1E)               // 4096 slots per tile

// ---------------------------------------------------------------------------
// K0: convert x -> fp16 mirror (in d_out scratch); zero stats(512f)+deg(N int)
// ---------------------------------------------------------------------------
__global__ void convert_zero(const float* __restrict__ x, __half* __restrict__ xh,
                             int* __restrict__ zbase /* stats..deg contiguous */) {
    int gid = blockIdx.x * blockDim.x + threadIdx.x;
    if (gid < 512 + N_NODES) zbase[gid] = 0;
    const int n4 = N_NODES * (D / 4);          // 3.2M float4 chunks
    if (gid < n4) {
        float4 v = ((const float4*)x)[gid];
        __half2 h0 = __float22half2_rn(make_float2(v.x, v.y));
        __half2 h1 = __float22half2_rn(make_float2(v.z, v.w));
        ((__half2*)xh)[(long long)gid * 2 + 0] = h0;
        ((__half2*)xh)[(long long)gid * 2 + 1] = h1;
    }
}

// ---------------------------------------------------------------------------
// K1: degree histogram, 4 edges/thread (no-return atomics pipeline freely)
// ---------------------------------------------------------------------------
#define HB 4
__global__ void histo(const int* __restrict__ ei, int* __restrict__ deg) {
    const int S = EDGES / HB;                  // 400000
    int i = blockIdx.x * blockDim.x + threadIdx.x;
    if (i >= S) return;
    int s[HB], d[HB];
#pragma unroll
    for (int j = 0; j < HB; ++j) {
        s[j] = ei[i + j * S];
        d[j] = ei[EDGES + i + j * S];
    }
#pragma unroll
    for (int j = 0; j < HB; ++j) atomicAdd(&deg[s[j]], 1);
#pragma unroll
    for (int j = 0; j < HB; ++j) atomicAdd(&deg[d[j]], 1);
}

// ---------------------------------------------------------------------------
// K2: exclusive prefix sum of deg -> off; seed bucket cursors gcur[b]=off[256b]
// ---------------------------------------------------------------------------
__global__ void scan_offsets(const int* __restrict__ deg, int* __restrict__ off,
                             int* __restrict__ gcur) {
    const int T = 1024;
    const int CH = (N_NODES + T - 1) / T;   // 98
    __shared__ int sums[T];
    int t = threadIdx.x;
    int base = t * CH;
    int s = 0;
    for (int i = 0; i < CH; ++i) {
        int idx = base + i;
        if (idx < N_NODES) s += deg[idx];
    }
    sums[t] = s;
    __syncthreads();
    for (int d = 1; d < T; d <<= 1) {
        int v = 0;
        if (t >= d) v = sums[t - d];
        __syncthreads();
        if (t >= d) sums[t] += v;
        __syncthreads();
    }
    int run = (t > 0) ? sums[t - 1] : 0;
    for (int i = 0; i < CH; ++i) {
        int idx = base + i;
        if (idx < N_NODES) {
            off[idx] = run;
            if ((idx & 255) == 0) gcur[idx >> 8] = run;
            run += deg[idx];
        }
    }
    if (t == T - 1) off[N_NODES] = run;
}

// ---------------------------------------------------------------------------
// K3a: partition slots into 391 coarse buckets (node>>8).
// slot t in [0,2E): val = ei[t]; node = ei[t<E ? t+E : t-E]
// LDS-atomic local ranks; ONE returning global atomic per (tile,bucket).
// ---------------------------------------------------------------------------
__launch_bounds__(256)
__global__ void partition_pairs(const int* __restrict__ ei, int* __restrict__ gcur,
                                int2* __restrict__ pairs) {
    __shared__ int cnt[NB];
    __shared__ int cbase[NB];
    const int tid = threadIdx.x;
    for (int i = tid; i < NB; i += 256) cnt[i] = 0;
    __syncthreads();

    int bb[L1E], rr[L1E], nd[L1E], vl[L1E];
    const int t0 = blockIdx.x * L1TILE + tid;
#pragma unroll
    for (int j = 0; j < L1E; ++j) {
        int t = t0 + j * 256;
        bb[j] = -1;
        if (t < 2 * EDGES) {
            vl[j] = ei[t];
            int pt = (t < EDGES) ? t + EDGES : t - EDGES;
            nd[j] = ei[pt];
            bb[j] = nd[j] >> 8;
            rr[j] = atomicAdd(&cnt[bb[j]], 1);
        }
    }
    __syncthreads();
    for (int i = tid; i < NB; i += 256) {
        int c = cnt[i];
        cbase[i] = c ? atomicAdd(&gcur[i], c) : 0;
    }
    __syncthreads();
#pragma unroll
    for (int j = 0; j < L1E; ++j) {
        if (bb[j] >= 0) {
            pairs[cbase[bb[j]] + rr[j]] = make_int2(nd[j], vl[j]);
        }
    }
}

// ---------------------------------------------------------------------------
// K3b: per-bucket exact CSR fill via LDS cursors (no global atomics).
// block b handles pairs[off[256b] .. off[min(256b+256,N)])
// ---------------------------------------------------------------------------
__launch_bounds__(256)
__global__ void bucket_fill(const int2* __restrict__ pairs, const int* __restrict__ off,
                            int* __restrict__ adj) {
    __shared__ int soff[256];
    __shared__ int lcur[256];
    const int b   = blockIdx.x;
    const int n0  = b << 8;
    const int nEnd = min(n0 + 256, N_NODES);
    const int cn  = nEnd - n0;
    const int tid = threadIdx.x;
    if (tid < cn) { soff[tid] = off[n0 + tid]; lcur[tid] = 0; }
    __syncthreads();
    const int s0 = off[n0];
    const int s1 = off[nEnd];
    for (int i = s0 + tid; i < s1; i += 256) {
        int2 p = pairs[i];
        int ln = p.x - n0;
        int r = atomicAdd(&lcur[ln], 1);
        adj[soff[ln] + r] = p.y;
    }
}

// ---------------------------------------------------------------------------
// K4: h_pre[v] = (2+eps)*x[v](fp32) + sum_{u in adj(v)} xh[u](fp16)
// one wave per node; lane = one half2 pair; 4 outstanding row reads
// ---------------------------------------------------------------------------
__launch_bounds__(256)
__global__ void gather_aggr(const float* __restrict__ x, const __half* __restrict__ xh,
                            const int* __restrict__ adj, const int* __restrict__ off,
                            const float* __restrict__ eps_p, float* __restrict__ hpre) {
    int node = blockIdx.x * 4 + (threadIdx.x >> 6);
    int lane = threadIdx.x & 63;
    if (node >= N_NODES) return;
    int b = off[node];
    int e = off[node + 1];
    const __half2* xp = (const __half2*)xh;
    float ax = 0.f, ay = 0.f;
    int i = b;
    for (; i + 4 <= e; i += 4) {               // 4 independent 256B row reads
        int n0 = adj[i], n1 = adj[i + 1], n2 = adj[i + 2], n3 = adj[i + 3];
        __half2 v0 = xp[(long long)n0 * 64 + lane];
        __half2 v1 = xp[(long long)n1 * 64 + lane];
        __half2 v2 = xp[(long long)n2 * 64 + lane];
        __half2 v3 = xp[(long long)n3 * 64 + lane];
        float2 f0 = __half22float2(v0);
        float2 f1 = __half22float2(v1);
        float2 f2 = __half22float2(v2);
        float2 f3 = __half22float2(v3);
        ax += (f0.x + f1.x) + (f2.x + f3.x);
        ay += (f0.y + f1.y) + (f2.y + f3.y);
    }
    for (; i < e; ++i) {
        __half2 v = xp[(long long)adj[i] * 64 + lane];
        float2 f = __half22float2(v);
        ax += f.x;
        ay += f.y;
    }
    float2 xs = ((const float2*)x)[(long long)node * 64 + lane];
    float sc = 2.0f + eps_p[0];
    float2 o;
    o.x = fmaf(sc, xs.x, ax);
    o.y = fmaf(sc, xs.y, ay);
    ((float2*)hpre)[(long long)node * 64 + lane] = o;
}

// ---------------------------------------------------------------------------
// K5: h1 = h_pre @ W1^T + b1  (into d_out) + BN sum/sumsq stats
// ---------------------------------------------------------------------------
__launch_bounds__(256)
__global__ void gemm1_stats(const float* __restrict__ hpre, const float* __restrict__ W1,
                            const float* __restrict__ b1, float* __restrict__ h1,
                            float* __restrict__ stats) {
    __shared__ __align__(16) float sA[TM][136];
    __shared__ float sPart[2][8][128];
    const int tid  = threadIdx.x;
    const int tx   = tid & 31;
    const int ty   = tid >> 5;
    const int row0 = blockIdx.x * TM;

#pragma unroll
    for (int i = 0; i < 8; ++i) {
        int f = tid + 256 * i;
        int r = f >> 5, c4 = f & 31;
        int gr = row0 + r;
        float4 v = make_float4(0.f, 0.f, 0.f, 0.f);
        if (gr < N_NODES) v = *(const float4*)(hpre + (long long)gr * D + c4 * 4);
        *(float4*)&sA[r][c4 * 4] = v;
    }
    __syncthreads();

    float acc[8][4];
#pragma unroll
    for (int j = 0; j < 8; ++j)
#pragma unroll
        for (int q = 0; q < 4; ++q) acc[j][q] = 0.f;

    const float* w0p = W1 + (tx * 4 + 0) * D;
    const float* w1p = W1 + (tx * 4 + 1) * D;
    const float* w2p = W1 + (tx * 4 + 2) * D;
    const float* w3p = W1 + (tx * 4 + 3) * D;

#pragma unroll 4
    for (int k4 = 0; k4 < 32; ++k4) {
        float4 w0 = *(const float4*)(w0p + k4 * 4);
        float4 w1 = *(const float4*)(w1p + k4 * 4);
        float4 w2 = *(const float4*)(w2p + k4 * 4);
        float4 w3 = *(const float4*)(w3p + k4 * 4);
#pragma unroll
        for (int j = 0; j < 8; ++j) {
            float4 a = *(const float4*)&sA[ty * 8 + j][k4 * 4];
            acc[j][0] = fmaf(a.x, w0.x, fmaf(a.y, w0.y, fmaf(a.z, w0.z, fmaf(a.w, w0.w, acc[j][0]))));
            acc[j][1] = fmaf(a.x, w1.x, fmaf(a.y, w1.y, fmaf(a.z, w1.z, fmaf(a.w, w1.w, acc[j][1]))));
            acc[j][2] = fmaf(a.x, w2.x, fmaf(a.y, w2.y, fmaf(a.z, w2.z, fmaf(a.w, w2.w, acc[j][2]))));
            acc[j][3] = fmaf(a.x, w3.x, fmaf(a.y, w3.y, fmaf(a.z, w3.z, fmaf(a.w, w3.w, acc[j][3]))));
        }
    }

    float4 bb = *(const float4*)(b1 + tx * 4);
    float psum[4] = {0.f, 0.f, 0.f, 0.f};
    float psq[4]  = {0.f, 0.f, 0.f, 0.f};
#pragma unroll
    for (int j = 0; j < 8; ++j) {
        int gr = row0 + ty * 8 + j;
        if (gr < N_NODES) {
            float4 o;
            o.x = acc[j][0] + bb.x;
            o.y = acc[j][1] + bb.y;
            o.z = acc[j][2] + bb.z;
            o.w = acc[j][3] + bb.w;
            *(float4*)(h1 + (long long)gr * D + tx * 4) = o;
            psum[0] += o.x; psum[1] += o.y; psum[2] += o.z; psum[3] += o.w;
            psq[0] += o.x * o.x; psq[1] += o.y * o.y;
            psq[2] += o.z * o.z; psq[3] += o.w * o.w;
        }
    }
#pragma unroll
    for (int q = 0; q < 4; ++q) {
        sPart[0][ty][tx * 4 + q] = psum[q];
        sPart[1][ty][tx * 4 + q] = psq[q];
    }
    __syncthreads();
    if (tid < 128) {
        float s = 0.f, ss = 0.f;
#pragma unroll
        for (int t = 0; t < 8; ++t) { s += sPart[0][t][tid]; ss += sPart[1][t][tid]; }
        atomicAdd(&stats[tid], s);
        atomicAdd(&stats[128 + tid], ss);
    }
}

// ---------------------------------------------------------------------------
// K6: out = relu(bn(h1)) @ W2^T + b2  -- in-place on d_out; BN finalize fused
// ---------------------------------------------------------------------------
__launch_bounds__(256)
__global__ void bn_relu_gemm2(float* __restrict__ h1out, const float* __restrict__ W2,
                              const float* __restrict__ b2, const float* __restrict__ stats,
                              const float* __restrict__ gamma, const float* __restrict__ beta) {
    __shared__ __align__(16) float sA[TM][136];
    __shared__ __align__(16) float sScale[128];
    __shared__ __align__(16) float sShift[128];
    const int tid  = threadIdx.x;
    const int tx   = tid & 31;
    const int ty   = tid >> 5;
    const int row0 = blockIdx.x * TM;

    if (tid < 128) {
        float mean = stats[tid] * (1.0f / N_NODES);
        float var  = fmaxf(stats[128 + tid] * (1.0f / N_NODES) - mean * mean, 0.0f);
        float s    = gamma[tid] * rsqrtf(var + BN_EPS);
        sScale[tid] = s;
        sShift[tid] = beta[tid] - mean * s;
    }
    __syncthreads();

#pragma unroll
    for (int i = 0; i < 8; ++i) {
        int f = tid + 256 * i;
        int r = f >> 5, c4 = f & 31;
        int gr = row0 + r;
        float4 v = make_float4(0.f, 0.f, 0.f, 0.f);
        if (gr < N_NODES) {
            v = *(const float4*)(h1out + (long long)gr * D + c4 * 4);
            float4 sc = *(const float4*)&sScale[c4 * 4];
            float4 sh = *(const float4*)&sShift[c4 * 4];
            v.x = fmaxf(0.f, fmaf(v.x, sc.x, sh.x));
            v.y = fmaxf(0.f, fmaf(v.y, sc.y, sh.y));
            v.z = fmaxf(0.f, fmaf(v.z, sc.z, sh.z));
            v.w = fmaxf(0.f, fmaf(v.w, sc.w, sh.w));
        }
        *(float4*)&sA[r][c4 * 4] = v;
    }
    __syncthreads();

    float acc[8][4];
#pragma unroll
    for (int j = 0; j < 8; ++j)
#pragma unroll
        for (int q = 0; q < 4; ++q) acc[j][q] = 0.f;

    const float* w0p = W2 + (tx * 4 + 0) * D;
    const float* w1p = W2 + (tx * 4 + 1) * D;
    const float* w2p = W2 + (tx * 4 + 2) * D;
    const float* w3p = W2 + (tx * 4 + 3) * D;

#pragma unroll 4
    for (int k4 = 0; k4 < 32; ++k4) {
        float4 w0 = *(const float4*)(w0p + k4 * 4);
        float4 w1 = *(const float4*)(w1p + k4 * 4);
        float4 w2 = *(const float4*)(w2p + k4 * 4);
        float4 w3 = *(const float4*)(w3p + k4 * 4);
#pragma unroll
        for (int j = 0; j < 8; ++j) {
            float4 a = *(const float4*)&sA[ty * 8 + j][k4 * 4];
            acc[j][0] = fmaf(a.x, w0.x, fmaf(a.y, w0.y, fmaf(a.z, w0.z, fmaf(a.w, w0.w, acc[j][0]))));
            acc[j][1] = fmaf(a.x, w1.x, fmaf(a.y, w1.y, fmaf(a.z, w1.z, fmaf(a.w, w1.w, acc[j][1]))));
            acc[j][2] = fmaf(a.x, w2.x, fmaf(a.y, w2.y, fmaf(a.z, w2.z, fmaf(a.w, w2.w, acc[j][2]))));
            acc[j][3] = fmaf(a.x, w3.x, fmaf(a.y, w3.y, fmaf(a.z, w3.z, fmaf(a.w, w3.w, acc[j][3]))));
        }
    }

    float4 bb = *(const float4*)(b2 + tx * 4);
#pragma unroll
    for (int j = 0; j < 8; ++j) {
        int gr = row0 + ty * 8 + j;
        if (gr < N_NODES) {
            float4 o;
            o.x = acc[j][0] + bb.x;
            o.y = acc[j][1] + bb.y;
            o.z = acc[j][2] + bb.z;
            o.w = acc[j][3] + bb.w;
            *(float4*)(h1out + (long long)gr * D + tx * 4) = o;
        }
    }
}

// ---------------------------------------------------------------------------
extern "C" void kernel_launch(void* const* d_in, const int* in_sizes, int n_in,
                              void* d_out, int out_size, void* d_ws, size_t ws_size,
                              hipStream_t stream) {
    const float* x     = (const float*)d_in[0];
    const int*   ei    = (const int*)d_in[1];
    const float* eps_p = (const float*)d_in[2];
    const float* W1    = (const float*)d_in[3];
    const float* b1    = (const float*)d_in[4];
    const float* gamma = (const float*)d_in[5];
    const float* beta  = (const float*)d_in[6];
    const float* W2    = (const float*)d_in[7];
    const float* b2    = (const float*)d_in[8];

    // workspace layout (~65 MB)
    float* aggr  = (float*)d_ws;                        // N*128 floats (h_pre)
    float* stats = aggr + (long long)N_NODES * D;       // 512 floats
    int*   deg   = (int*)(stats + 512);                 // N ints (contiguous after stats)
    int*   off   = deg + N_NODES;                       // N+1 ints
    int*   gcur  = off + N_NODES + 1;                   // NB ints (bucket cursors)
    int*   adj   = gcur + 512;                          // 2E ints
    float* out   = (float*)d_out;                       // h1 scratch + final out
    __half* xh   = (__half*)d_out;                      // fp16 mirror: d_out[0 : 25.6MB]
    int2*  pairs = (int2*)(out + (long long)N_NODES * (D / 2)); // d_out[25.6 : 51.2MB]

    {   // K0: fp16 convert + zero stats/deg
        int grid = (N_NODES * (D / 4) + 255) / 256;
        convert_zero<<<grid, 256, 0, stream>>>(x, xh, (int*)stats);
    }
    {   // K1: degree histogram (4 edges/thread, fire-and-forget atomics)
        int grid = (EDGES / HB + 255) / 256;
        histo<<<grid, 256, 0, stream>>>(ei, deg);
    }
    {   // K2: prefix sum -> off; seed bucket cursors
        scan_offsets<<<1, 1024, 0, stream>>>(deg, off, gcur);
    }
    {   // K3a: coarse-bucket partition (LDS ranks + 1 global atomic per tile-bucket)
        int grid = (2 * EDGES + L1TILE - 1) / L1TILE;   // 782
        partition_pairs<<<grid, 256, 0, stream>>>(ei, gcur, pairs);
    }
    {   // K3b: exact CSR fill inside each bucket (LDS cursors only)
        bucket_fill<<<NB, 256, 0, stream>>>(pairs, off, adj);
    }
    {   // K4: gather-aggregate (fp16 neighbor reads, 4-deep MLP)
        int grid = (N_NODES + 3) / 4;
        gather_aggr<<<grid, 256, 0, stream>>>(x, xh, adj, off, eps_p, aggr);
    }
    {   // K5: GEMM1 + BN stats (h1 -> d_out, overwrites xh/pairs)
        int grid = (N_NODES + TM - 1) / TM;
        gemm1_stats<<<grid, 256, 0, stream>>>(aggr, W1, b1, out, stats);
    }
    {   // K6: BN finalize + ReLU + GEMM2, in-place on d_out
        int grid = (N_NODES + TM - 1) / TM;
        bn_relu_gemm2<<<grid, 256, 0, stream>>>(out, W2, b2, stats, gamma, beta);
    }
}

// Round 6
// 715.414 us; speedup vs baseline: 7.9926x; 1.2667x over previous
//
#include <hip/hip_runtime.h>
#include <hip/hip_fp16.h>

#define N_NODES 100000
#define EDGES   1600000
#define D       128
#define BN_EPS  1e-5f
#define TM      64                        // rows per GEMM block
#define NB      ((N_NODES + 255) >> 8)    // 391 coarse buckets (256 nodes each)
#define L1E     16                        // slots per thread in partition pass
#define L1TILE  (256 * L1E)               // 4096 slots per tile

// ---------------------------------------------------------------------------
// K0: convert x -> fp16 mirror (in d_out scratch); zero stats(512f)+deg(N int)
// ---------------------------------------------------------------------------
__global__ void convert_zero(const float* __restrict__ x, __half* __restrict__ xh,
                             int* __restrict__ zbase /* stats..deg contiguous */) {
    int gid = blockIdx.x * blockDim.x + threadIdx.x;
    if (gid < 512 + N_NODES) zbase[gid] = 0;
    const int n4 = N_NODES * (D / 4);          // 3.2M float4 chunks
    if (gid < n4) {
        float4 v = ((const float4*)x)[gid];
        __half2 h0 = __float22half2_rn(make_float2(v.x, v.y));
        __half2 h1 = __float22half2_rn(make_float2(v.z, v.w));
        ((__half2*)xh)[(long long)gid * 2 + 0] = h0;
        ((__half2*)xh)[(long long)gid * 2 + 1] = h1;
    }
}

// ---------------------------------------------------------------------------
// K1: degree histogram, 4 edges/thread (no-return atomics pipeline freely)
// ---------------------------------------------------------------------------
#define HB 4
__global__ void histo(const int* __restrict__ ei, int* __restrict__ deg) {
    const int S = EDGES / HB;                  // 400000
    int i = blockIdx.x * blockDim.x + threadIdx.x;
    if (i >= S) return;
    int s[HB], d[HB];
#pragma unroll
    for (int j = 0; j < HB; ++j) {
        s[j] = ei[i + j * S];
        d[j] = ei[EDGES + i + j * S];
    }
#pragma unroll
    for (int j = 0; j < HB; ++j) atomicAdd(&deg[s[j]], 1);
#pragma unroll
    for (int j = 0; j < HB; ++j) atomicAdd(&deg[d[j]], 1);
}

// ---------------------------------------------------------------------------
// K2a: per-bucket degree sums (391 blocks x 256) -> bsum[b]
// ---------------------------------------------------------------------------
__global__ void bucket_sums(const int* __restrict__ deg, int* __restrict__ bsum) {
    __shared__ int red[256];
    const int b = blockIdx.x;
    const int t = threadIdx.x;
    const int n = (b << 8) + t;
    red[t] = (n < N_NODES) ? deg[n] : 0;
    __syncthreads();
#pragma unroll
    for (int s = 128; s > 0; s >>= 1) {
        if (t < s) red[t] += red[t + s];
        __syncthreads();
    }
    if (t == 0) bsum[b] = red[0];
}

// ---------------------------------------------------------------------------
// K2b: exclusive scan of 391 bucket sums (single 512-thread block) -> bbase
// ---------------------------------------------------------------------------
__global__ void scan_bsums(const int* __restrict__ bsum, int* __restrict__ bbase) {
    __shared__ int s[512];
    const int t = threadIdx.x;
    s[t] = (t < NB) ? bsum[t] : 0;
    __syncthreads();
    for (int d = 1; d < 512; d <<= 1) {
        int u = (t >= d) ? s[t - d] : 0;
        __syncthreads();
        s[t] += u;
        __syncthreads();
    }
    if (t < NB) bbase[t] = (t > 0) ? s[t - 1] : 0;
}

// ---------------------------------------------------------------------------
// K2c: per-bucket local scan -> off[n]; seed gcur[b]=bbase[b]; off[N]=2E
// ---------------------------------------------------------------------------
__global__ void scan_local(const int* __restrict__ deg, const int* __restrict__ bbase,
                           int* __restrict__ off, int* __restrict__ gcur) {
    __shared__ int s[256];
    const int b = blockIdx.x;
    const int t = threadIdx.x;
    const int n = (b << 8) + t;
    s[t] = (n < N_NODES) ? deg[n] : 0;
    __syncthreads();
    for (int d = 1; d < 256; d <<= 1) {
        int u = (t >= d) ? s[t - d] : 0;
        __syncthreads();
        s[t] += u;
        __syncthreads();
    }
    const int base = bbase[b];
    if (n < N_NODES) off[n] = base + ((t > 0) ? s[t - 1] : 0);
    if (t == 0) gcur[b] = base;
    if (b == 0 && t == 0) off[N_NODES] = 2 * EDGES;
}

// ---------------------------------------------------------------------------
// K3a: partition slots into 391 coarse buckets (node>>8).
// slot t in [0,2E): val = ei[t]; node = ei[t<E ? t+E : t-E]
// LDS-atomic local ranks; ONE returning global atomic per (tile,bucket).
// ---------------------------------------------------------------------------
__launch_bounds__(256)
__global__ void partition_pairs(const int* __restrict__ ei, int* __restrict__ gcur,
                                int2* __restrict__ pairs) {
    __shared__ int cnt[NB];
    __shared__ int cbase[NB];
    const int tid = threadIdx.x;
    for (int i = tid; i < NB; i += 256) cnt[i] = 0;
    __syncthreads();

    int bb[L1E], rr[L1E], nd[L1E], vl[L1E];
    const int t0 = blockIdx.x * L1TILE + tid;
#pragma unroll
    for (int j = 0; j < L1E; ++j) {
        int t = t0 + j * 256;
        bb[j] = -1;
        if (t < 2 * EDGES) {
            vl[j] = ei[t];
            int pt = (t < EDGES) ? t + EDGES : t - EDGES;
            nd[j] = ei[pt];
            bb[j] = nd[j] >> 8;
            rr[j] = atomicAdd(&cnt[bb[j]], 1);
        }
    }
    __syncthreads();
    for (int i = tid; i < NB; i += 256) {
        int c = cnt[i];
        cbase[i] = c ? atomicAdd(&gcur[i], c) : 0;
    }
    __syncthreads();
#pragma unroll
    for (int j = 0; j < L1E; ++j) {
        if (bb[j] >= 0) {
            pairs[cbase[bb[j]] + rr[j]] = make_int2(nd[j], vl[j]);
        }
    }
}

// ---------------------------------------------------------------------------
// K3b: per-bucket exact CSR fill via LDS cursors (no global atomics).
// ---------------------------------------------------------------------------
__launch_bounds__(256)
__global__ void bucket_fill(const int2* __restrict__ pairs, const int* __restrict__ off,
                            int* __restrict__ adj) {
    __shared__ int soff[256];
    __shared__ int lcur[256];
    const int b   = blockIdx.x;
    const int n0  = b << 8;
    const int nEnd = min(n0 + 256, N_NODES);
    const int cn  = nEnd - n0;
    const int tid = threadIdx.x;
    if (tid < cn) { soff[tid] = off[n0 + tid]; lcur[tid] = 0; }
    __syncthreads();
    const int s0 = off[n0];
    const int s1 = off[nEnd];
    for (int i = s0 + tid; i < s1; i += 256) {
        int2 p = pairs[i];
        int ln = p.x - n0;
        int r = atomicAdd(&lcur[ln], 1);
        adj[soff[ln] + r] = p.y;
    }
}

// ---------------------------------------------------------------------------
// K4: h_pre[v] = (2+eps)*x[v](fp32) + sum_{u in adj(v)} xh[u](fp16)
// ---------------------------------------------------------------------------
__launch_bounds__(256)
__global__ void gather_aggr(const float* __restrict__ x, const __half* __restrict__ xh,
                            const int* __restrict__ adj, const int* __restrict__ off,
                            const float* __restrict__ eps_p, float* __restrict__ hpre) {
    int node = blockIdx.x * 4 + (threadIdx.x >> 6);
    int lane = threadIdx.x & 63;
    if (node >= N_NODES) return;
    int b = off[node];
    int e = off[node + 1];
    const __half2* xp = (const __half2*)xh;
    float ax = 0.f, ay = 0.f;
    int i = b;
    for (; i + 4 <= e; i += 4) {               // 4 independent 256B row reads
        int n0 = adj[i], n1 = adj[i + 1], n2 = adj[i + 2], n3 = adj[i + 3];
        __half2 v0 = xp[(long long)n0 * 64 + lane];
        __half2 v1 = xp[(long long)n1 * 64 + lane];
        __half2 v2 = xp[(long long)n2 * 64 + lane];
        __half2 v3 = xp[(long long)n3 * 64 + lane];
        float2 f0 = __half22float2(v0);
        float2 f1 = __half22float2(v1);
        float2 f2 = __half22float2(v2);
        float2 f3 = __half22float2(v3);
        ax += (f0.x + f1.x) + (f2.x + f3.x);
        ay += (f0.y + f1.y) + (f2.y + f3.y);
    }
    for (; i < e; ++i) {
        __half2 v = xp[(long long)adj[i] * 64 + lane];
        float2 f = __half22float2(v);
        ax += f.x;
        ay += f.y;
    }
    float2 xs = ((const float2*)x)[(long long)node * 64 + lane];
    float sc = 2.0f + eps_p[0];
    float2 o;
    o.x = fmaf(sc, xs.x, ax);
    o.y = fmaf(sc, xs.y, ay);
    ((float2*)hpre)[(long long)node * 64 + lane] = o;
}

// ---------------------------------------------------------------------------
// K5: h1 = h_pre @ W1^T + b1  (into d_out) + BN sum/sumsq stats
// ---------------------------------------------------------------------------
__launch_bounds__(256)
__global__ void gemm1_stats(const float* __restrict__ hpre, const float* __restrict__ W1,
                            const float* __restrict__ b1, float* __restrict__ h1,
                            float* __restrict__ stats) {
    __shared__ __align__(16) float sA[TM][136];
    __shared__ float sPart[2][8][128];
    const int tid  = threadIdx.x;
    const int tx   = tid & 31;
    const int ty   = tid >> 5;
    const int row0 = blockIdx.x * TM;

#pragma unroll
    for (int i = 0; i < 8; ++i) {
        int f = tid + 256 * i;
        int r = f >> 5, c4 = f & 31;
        int gr = row0 + r;
        float4 v = make_float4(0.f, 0.f, 0.f, 0.f);
        if (gr < N_NODES) v = *(const float4*)(hpre + (long long)gr * D + c4 * 4);
        *(float4*)&sA[r][c4 * 4] = v;
    }
    __syncthreads();

    float acc[8][4];
#pragma unroll
    for (int j = 0; j < 8; ++j)
#pragma unroll
        for (int q = 0; q < 4; ++q) acc[j][q] = 0.f;

    const float* w0p = W1 + (tx * 4 + 0) * D;
    const float* w1p = W1 + (tx * 4 + 1) * D;
    const float* w2p = W1 + (tx * 4 + 2) * D;
    const float* w3p = W1 + (tx * 4 + 3) * D;

#pragma unroll 4
    for (int k4 = 0; k4 < 32; ++k4) {
        float4 w0 = *(const float4*)(w0p + k4 * 4);
        float4 w1 = *(const float4*)(w1p + k4 * 4);
        float4 w2 = *(const float4*)(w2p + k4 * 4);
        float4 w3 = *(const float4*)(w3p + k4 * 4);
#pragma unroll
        for (int j = 0; j < 8; ++j) {
            float4 a = *(const float4*)&sA[ty * 8 + j][k4 * 4];
            acc[j][0] = fmaf(a.x, w0.x, fmaf(a.y, w0.y, fmaf(a.z, w0.z, fmaf(a.w, w0.w, acc[j][0]))));
            acc[j][1] = fmaf(a.x, w1.x, fmaf(a.y, w1.y, fmaf(a.z, w1.z, fmaf(a.w, w1.w, acc[j][1]))));
            acc[j][2] = fmaf(a.x, w2.x, fmaf(a.y, w2.y, fmaf(a.z, w2.z, fmaf(a.w, w2.w, acc[j][2]))));
            acc[j][3] = fmaf(a.x, w3.x, fmaf(a.y, w3.y, fmaf(a.z, w3.z, fmaf(a.w, w3.w, acc[j][3]))));
        }
    }

    float4 bb = *(const float4*)(b1 + tx * 4);
    float psum[4] = {0.f, 0.f, 0.f, 0.f};
    float psq[4]  = {0.f, 0.f, 0.f, 0.f};
#pragma unroll
    for (int j = 0; j < 8; ++j) {
        int gr = row0 + ty * 8 + j;
        if (gr < N_NODES) {
            float4 o;
            o.x = acc[j][0] + bb.x;
            o.y = acc[j][1] + bb.y;
            o.z = acc[j][2] + bb.z;
            o.w = acc[j][3] + bb.w;
            *(float4*)(h1 + (long long)gr * D + tx * 4) = o;
            psum[0] += o.x; psum[1] += o.y; psum[2] += o.z; psum[3] += o.w;
            psq[0] += o.x * o.x; psq[1] += o.y * o.y;
            psq[2] += o.z * o.z; psq[3] += o.w * o.w;
        }
    }
#pragma unroll
    for (int q = 0; q < 4; ++q) {
        sPart[0][ty][tx * 4 + q] = psum[q];
        sPart[1][ty][tx * 4 + q] = psq[q];
    }
    __syncthreads();
    if (tid < 128) {
        float s = 0.f, ss = 0.f;
#pragma unroll
        for (int t = 0; t < 8; ++t) { s += sPart[0][t][tid]; ss += sPart[1][t][tid]; }
        atomicAdd(&stats[tid], s);
        atomicAdd(&stats[128 + tid], ss);
    }
}

// ---------------------------------------------------------------------------
// K6: out = relu(bn(h1)) @ W2^T + b2  -- in-place on d_out; BN finalize fused
// ---------------------------------------------------------------------------
__launch_bounds__(256)
__global__ void bn_relu_gemm2(float* __restrict__ h1out, const float* __restrict__ W2,
                              const float* __restrict__ b2, const float* __restrict__ stats,
                              const float* __restrict__ gamma, const float* __restrict__ beta) {
    __shared__ __align__(16) float sA[TM][136];
    __shared__ __align__(16) float sScale[128];
    __shared__ __align__(16) float sShift[128];
    const int tid  = threadIdx.x;
    const int tx   = tid & 31;
    const int ty   = tid >> 5;
    const int row0 = blockIdx.x * TM;

    if (tid < 128) {
        float mean = stats[tid] * (1.0f / N_NODES);
        float var  = fmaxf(stats[128 + tid] * (1.0f / N_NODES) - mean * mean, 0.0f);
        float s    = gamma[tid] * rsqrtf(var + BN_EPS);
        sScale[tid] = s;
        sShift[tid] = beta[tid] - mean * s;
    }
    __syncthreads();

#pragma unroll
    for (int i = 0; i < 8; ++i) {
        int f = tid + 256 * i;
        int r = f >> 5, c4 = f & 31;
        int gr = row0 + r;
        float4 v = make_float4(0.f, 0.f, 0.f, 0.f);
        if (gr < N_NODES) {
            v = *(const float4*)(h1out + (long long)gr * D + c4 * 4);
            float4 sc = *(const float4*)&sScale[c4 * 4];
            float4 sh = *(const float4*)&sShift[c4 * 4];
            v.x = fmaxf(0.f, fmaf(v.x, sc.x, sh.x));
            v.y = fmaxf(0.f, fmaf(v.y, sc.y, sh.y));
            v.z = fmaxf(0.f, fmaf(v.z, sc.z, sh.z));
            v.w = fmaxf(0.f, fmaf(v.w, sc.w, sh.w));
        }
        *(float4*)&sA[r][c4 * 4] = v;
    }
    __syncthreads();

    float acc[8][4];
#pragma unroll
    for (int j = 0; j < 8; ++j)
#pragma unroll
        for (int q = 0; q < 4; ++q) acc[j][q] = 0.f;

    const float* w0p = W2 + (tx * 4 + 0) * D;
    const float* w1p = W2 + (tx * 4 + 1) * D;
    const float* w2p = W2 + (tx * 4 + 2) * D;
    const float* w3p = W2 + (tx * 4 + 3) * D;

#pragma unroll 4
    for (int k4 = 0; k4 < 32; ++k4) {
        float4 w0 = *(const float4*)(w0p + k4 * 4);
        float4 w1 = *(const float4*)(w1p + k4 * 4);
        float4 w2 = *(const float4*)(w2p + k4 * 4);
        float4 w3 = *(const float4*)(w3p + k4 * 4);
#pragma unroll
        for (int j = 0; j < 8; ++j) {
            float4 a = *(const float4*)&sA[ty * 8 + j][k4 * 4];
            acc[j][0] = fmaf(a.x, w0.x, fmaf(a.y, w0.y, fmaf(a.z, w0.z, fmaf(a.w, w0.w, acc[j][0]))));
            acc[j][1] = fmaf(a.x, w1.x, fmaf(a.y, w1.y, fmaf(a.z, w1.z, fmaf(a.w, w1.w, acc[j][1]))));
            acc[j][2] = fmaf(a.x, w2.x, fmaf(a.y, w2.y, fmaf(a.z, w2.z, fmaf(a.w, w2.w, acc[j][2]))));
            acc[j][3] = fmaf(a.x, w3.x, fmaf(a.y, w3.y, fmaf(a.z, w3.z, fmaf(a.w, w3.w, acc[j][3]))));
        }
    }

    float4 bb = *(const float4*)(b2 + tx * 4);
#pragma unroll
    for (int j = 0; j < 8; ++j) {
        int gr = row0 + ty * 8 + j;
        if (gr < N_NODES) {
            float4 o;
            o.x = acc[j][0] + bb.x;
            o.y = acc[j][1] + bb.y;
            o.z = acc[j][2] + bb.z;
            o.w = acc[j][3] + bb.w;
            *(float4*)(h1out + (long long)gr * D + tx * 4) = o;
        }
    }
}

// ---------------------------------------------------------------------------
extern "C" void kernel_launch(void* const* d_in, const int* in_sizes, int n_in,
                              void* d_out, int out_size, void* d_ws, size_t ws_size,
                              hipStream_t stream) {
    const float* x     = (const float*)d_in[0];
    const int*   ei    = (const int*)d_in[1];
    const float* eps_p = (const float*)d_in[2];
    const float* W1    = (const float*)d_in[3];
    const float* b1    = (const float*)d_in[4];
    const float* gamma = (const float*)d_in[5];
    const float* beta  = (const float*)d_in[6];
    const float* W2    = (const float*)d_in[7];
    const float* b2    = (const float*)d_in[8];

    // workspace layout (~65 MB)
    float* aggr  = (float*)d_ws;                        // N*128 floats (h_pre)
    float* stats = aggr + (long long)N_NODES * D;       // 512 floats
    int*   deg   = (int*)(stats + 512);                 // N ints (contiguous after stats)
    int*   off   = deg + N_NODES;                       // N+1 ints
    int*   gcur  = off + N_NODES + 1;                   // NB ints (bucket cursors)
    int*   bsum  = gcur + 512;                          // NB ints
    int*   bbase = bsum + 512;                          // NB ints
    int*   adj   = bbase + 512;                         // 2E ints
    float* out   = (float*)d_out;                       // h1 scratch + final out
    __half* xh   = (__half*)d_out;                      // fp16 mirror: d_out[0 : 25.6MB]
    int2*  pairs = (int2*)(out + (long long)N_NODES * (D / 2)); // d_out[25.6 : 51.2MB]

    {   // K0: fp16 convert + zero stats/deg
        int grid = (N_NODES * (D / 4) + 255) / 256;
        convert_zero<<<grid, 256, 0, stream>>>(x, xh, (int*)stats);
    }
    {   // K1: degree histogram (4 edges/thread, fire-and-forget atomics)
        int grid = (EDGES / HB + 255) / 256;
        histo<<<grid, 256, 0, stream>>>(ei, deg);
    }
    {   // K2a-c: parallel 3-phase exclusive scan -> off, gcur
        bucket_sums<<<NB, 256, 0, stream>>>(deg, bsum);
        scan_bsums<<<1, 512, 0, stream>>>(bsum, bbase);
        scan_local<<<NB, 256, 0, stream>>>(deg, bbase, off, gcur);
    }
    {   // K3a: coarse-bucket partition (LDS ranks + 1 global atomic per tile-bucket)
        int grid = (2 * EDGES + L1TILE - 1) / L1TILE;   // 782
        partition_pairs<<<grid, 256, 0, stream>>>(ei, gcur, pairs);
    }
    {   // K3b: exact CSR fill inside each bucket (LDS cursors only)
        bucket_fill<<<NB, 256, 0, stream>>>(pairs, off, adj);
    }
    {   // K4: gather-aggregate (fp16 neighbor reads, 4-deep MLP)
        int grid = (N_NODES + 3) / 4;
        gather_aggr<<<grid, 256, 0, stream>>>(x, xh, adj, off, eps_p, aggr);
    }
    {   // K5: GEMM1 + BN stats (h1 -> d_out, overwrites xh/pairs)
        int grid = (N_NODES + TM - 1) / TM;
        gemm1_stats<<<grid, 256, 0, stream>>>(aggr, W1, b1, out, stats);
    }
    {   // K6: BN finalize + ReLU + GEMM2, in-place on d_out
        int grid = (N_NODES + TM - 1) / TM;
        bn_relu_gemm2<<<grid, 256, 0, stream>>>(out, W2, b2, stats, gamma, beta);
    }
}

// Round 7
// 628.553 us; speedup vs baseline: 9.0972x; 1.1382x over previous
//
#include <hip/hip_runtime.h>
#include <hip/hip_fp16.h>

#define N_NODES 100000
#define EDGES   1600000
#define D       128
#define BN_EPS  1e-5f
#define TM      64                        // rows per GEMM block
#define NB      ((N_NODES + 255) >> 8)    // 391 coarse buckets (256 nodes each)
#define L1E     16                        // slots per thread in partition pass
#define L1TILE  (256 * L1E)               // 4096 slots per tile

typedef __attribute__((ext_vector_type(8))) short short8;
typedef __attribute__((ext_vector_type(4))) float f32x4;

// round-to-nearest-even fp32 -> bf16 (bits), and bf16-bits -> fp32
__device__ __forceinline__ unsigned short bf_hi(float f) {
    unsigned u = __float_as_uint(f);
    unsigned t = u + 0x7FFF + ((u >> 16) & 1);
    return (unsigned short)(t >> 16);
}
__device__ __forceinline__ float bf_val(unsigned short h) {
    return __uint_as_float(((unsigned)h) << 16);
}

// ---------------------------------------------------------------------------
// K0: convert x -> fp16 mirror (in d_out scratch); zero stats(512f)+deg(N int)
// ---------------------------------------------------------------------------
__global__ void convert_zero(const float* __restrict__ x, __half* __restrict__ xh,
                             int* __restrict__ zbase) {
    int gid = blockIdx.x * blockDim.x + threadIdx.x;
    if (gid < 512 + N_NODES) zbase[gid] = 0;
    const int n4 = N_NODES * (D / 4);
    if (gid < n4) {
        float4 v = ((const float4*)x)[gid];
        __half2 h0 = __float22half2_rn(make_float2(v.x, v.y));
        __half2 h1 = __float22half2_rn(make_float2(v.z, v.w));
        ((__half2*)xh)[(long long)gid * 2 + 0] = h0;
        ((__half2*)xh)[(long long)gid * 2 + 1] = h1;
    }
}

// ---------------------------------------------------------------------------
// K1: degree histogram, 4 edges/thread
// ---------------------------------------------------------------------------
#define HB 4
__global__ void histo(const int* __restrict__ ei, int* __restrict__ deg) {
    const int S = EDGES / HB;
    int i = blockIdx.x * blockDim.x + threadIdx.x;
    if (i >= S) return;
    int s[HB], d[HB];
#pragma unroll
    for (int j = 0; j < HB; ++j) {
        s[j] = ei[i + j * S];
        d[j] = ei[EDGES + i + j * S];
    }
#pragma unroll
    for (int j = 0; j < HB; ++j) atomicAdd(&deg[s[j]], 1);
#pragma unroll
    for (int j = 0; j < HB; ++j) atomicAdd(&deg[d[j]], 1);
}

// ---------------------------------------------------------------------------
// K2a-c: 3-phase device-wide exclusive scan
// ---------------------------------------------------------------------------
__global__ void bucket_sums(const int* __restrict__ deg, int* __restrict__ bsum) {
    __shared__ int red[256];
    const int b = blockIdx.x, t = threadIdx.x;
    const int n = (b << 8) + t;
    red[t] = (n < N_NODES) ? deg[n] : 0;
    __syncthreads();
#pragma unroll
    for (int s = 128; s > 0; s >>= 1) {
        if (t < s) red[t] += red[t + s];
        __syncthreads();
    }
    if (t == 0) bsum[b] = red[0];
}

__global__ void scan_bsums(const int* __restrict__ bsum, int* __restrict__ bbase) {
    __shared__ int s[512];
    const int t = threadIdx.x;
    s[t] = (t < NB) ? bsum[t] : 0;
    __syncthreads();
    for (int d = 1; d < 512; d <<= 1) {
        int u = (t >= d) ? s[t - d] : 0;
        __syncthreads();
        s[t] += u;
        __syncthreads();
    }
    if (t < NB) bbase[t] = (t > 0) ? s[t - 1] : 0;
}

__global__ void scan_local(const int* __restrict__ deg, const int* __restrict__ bbase,
                           int* __restrict__ off, int* __restrict__ gcur) {
    __shared__ int s[256];
    const int b = blockIdx.x, t = threadIdx.x;
    const int n = (b << 8) + t;
    s[t] = (n < N_NODES) ? deg[n] : 0;
    __syncthreads();
    for (int d = 1; d < 256; d <<= 1) {
        int u = (t >= d) ? s[t - d] : 0;
        __syncthreads();
        s[t] += u;
        __syncthreads();
    }
    const int base = bbase[b];
    if (n < N_NODES) off[n] = base + ((t > 0) ? s[t - 1] : 0);
    if (t == 0) gcur[b] = base;
    if (b == 0 && t == 0) off[N_NODES] = 2 * EDGES;
}

// ---------------------------------------------------------------------------
// K2d: split W1/W2 into bf16 hi/lo (into dead deg region)
// ---------------------------------------------------------------------------
__global__ void split_w(const float* __restrict__ W1, const float* __restrict__ W2,
                        unsigned short* __restrict__ w1h, unsigned short* __restrict__ w1l,
                        unsigned short* __restrict__ w2h, unsigned short* __restrict__ w2l) {
    int i = blockIdx.x * blockDim.x + threadIdx.x;   // 0..32767
    if (i < 16384) {
        float f = W1[i];
        unsigned short h = bf_hi(f);
        w1h[i] = h;
        w1l[i] = bf_hi(f - bf_val(h));
    } else if (i < 32768) {
        int j = i - 16384;
        float f = W2[j];
        unsigned short h = bf_hi(f);
        w2h[j] = h;
        w2l[j] = bf_hi(f - bf_val(h));
    }
}

// ---------------------------------------------------------------------------
// K3a: coarse-bucket partition (LDS ranks + 1 returning atomic per tile-bucket)
// ---------------------------------------------------------------------------
__launch_bounds__(256)
__global__ void partition_pairs(const int* __restrict__ ei, int* __restrict__ gcur,
                                int2* __restrict__ pairs) {
    __shared__ int cnt[NB];
    __shared__ int cbase[NB];
    const int tid = threadIdx.x;
    for (int i = tid; i < NB; i += 256) cnt[i] = 0;
    __syncthreads();

    int bb[L1E], rr[L1E], nd[L1E], vl[L1E];
    const int t0 = blockIdx.x * L1TILE + tid;
#pragma unroll
    for (int j = 0; j < L1E; ++j) {
        int t = t0 + j * 256;
        bb[j] = -1;
        if (t < 2 * EDGES) {
            vl[j] = ei[t];
            int pt = (t < EDGES) ? t + EDGES : t - EDGES;
            nd[j] = ei[pt];
            bb[j] = nd[j] >> 8;
            rr[j] = atomicAdd(&cnt[bb[j]], 1);
        }
    }
    __syncthreads();
    for (int i = tid; i < NB; i += 256) {
        int c = cnt[i];
        cbase[i] = c ? atomicAdd(&gcur[i], c) : 0;
    }
    __syncthreads();
#pragma unroll
    for (int j = 0; j < L1E; ++j) {
        if (bb[j] >= 0) pairs[cbase[bb[j]] + rr[j]] = make_int2(nd[j], vl[j]);
    }
}

// ---------------------------------------------------------------------------
// K3b: per-bucket exact CSR fill via LDS cursors
// ---------------------------------------------------------------------------
__launch_bounds__(256)
__global__ void bucket_fill(const int2* __restrict__ pairs, const int* __restrict__ off,
                            int* __restrict__ adj) {
    __shared__ int soff[256];
    __shared__ int lcur[256];
    const int b   = blockIdx.x;
    const int n0  = b << 8;
    const int nEnd = min(n0 + 256, N_NODES);
    const int cn  = nEnd - n0;
    const int tid = threadIdx.x;
    if (tid < cn) { soff[tid] = off[n0 + tid]; lcur[tid] = 0; }
    __syncthreads();
    const int s0 = off[n0];
    const int s1 = off[nEnd];
    for (int i = s0 + tid; i < s1; i += 256) {
        int2 p = pairs[i];
        int ln = p.x - n0;
        int r = atomicAdd(&lcur[ln], 1);
        adj[soff[ln] + r] = p.y;
    }
}

// ---------------------------------------------------------------------------
// K4: gather-aggregate; emits h_pre as split bf16 (hi, lo) pair arrays
// ---------------------------------------------------------------------------
__launch_bounds__(256)
__global__ void gather_aggr(const float* __restrict__ x, const __half* __restrict__ xh,
                            const int* __restrict__ adj, const int* __restrict__ off,
                            const float* __restrict__ eps_p,
                            unsigned int* __restrict__ hh, unsigned int* __restrict__ hl) {
    int node = blockIdx.x * 4 + (threadIdx.x >> 6);
    int lane = threadIdx.x & 63;
    if (node >= N_NODES) return;
    int b = off[node];
    int e = off[node + 1];
    const __half2* xp = (const __half2*)xh;
    float ax = 0.f, ay = 0.f;
    int i = b;
    for (; i + 4 <= e; i += 4) {
        int n0 = adj[i], n1 = adj[i + 1], n2 = adj[i + 2], n3 = adj[i + 3];
        __half2 v0 = xp[(long long)n0 * 64 + lane];
        __half2 v1 = xp[(long long)n1 * 64 + lane];
        __half2 v2 = xp[(long long)n2 * 64 + lane];
        __half2 v3 = xp[(long long)n3 * 64 + lane];
        float2 f0 = __half22float2(v0);
        float2 f1 = __half22float2(v1);
        float2 f2 = __half22float2(v2);
        float2 f3 = __half22float2(v3);
        ax += (f0.x + f1.x) + (f2.x + f3.x);
        ay += (f0.y + f1.y) + (f2.y + f3.y);
    }
    for (; i < e; ++i) {
        __half2 v = xp[(long long)adj[i] * 64 + lane];
        float2 f = __half22float2(v);
        ax += f.x;
        ay += f.y;
    }
    float2 xs = ((const float2*)x)[(long long)node * 64 + lane];
    float sc = 2.0f + eps_p[0];
    float ox = fmaf(sc, xs.x, ax);
    float oy = fmaf(sc, xs.y, ay);
    unsigned short hx = bf_hi(ox), hy = bf_hi(oy);
    unsigned short lx = bf_hi(ox - bf_val(hx)), ly = bf_hi(oy - bf_val(hy));
    hh[(long long)node * 64 + lane] = (unsigned)hx | ((unsigned)hy << 16);
    hl[(long long)node * 64 + lane] = (unsigned)lx | ((unsigned)ly << 16);
}

// ---------------------------------------------------------------------------
// K5: h1 = h_pre @ W1^T + b1 (MFMA split-bf16, fp32-accurate) + BN stats
// block: 256 thr = 4 waves; wave w -> rows row0+16w..+15, 8 col-tiles of 16
// ---------------------------------------------------------------------------
__launch_bounds__(256)
__global__ void gemm1_mfma(const unsigned short* __restrict__ hh,
                           const unsigned short* __restrict__ hl,
                           const unsigned short* __restrict__ w1h,
                           const unsigned short* __restrict__ w1l,
                           const float* __restrict__ b1, float* __restrict__ h1,
                           float* __restrict__ stats) {
    __shared__ unsigned short sH[TM][136];
    __shared__ unsigned short sL[TM][136];
    __shared__ float sPart[2][4][128];
    const int tid = threadIdx.x;
    const int wv  = tid >> 6;
    const int ln  = tid & 63;
    const int lc  = ln & 15;
    const int qd  = ln >> 4;
    const int row0 = blockIdx.x * TM;

    // stage A hi/lo (16B chunks, coalesced)
#pragma unroll
    for (int i = 0; i < 4; ++i) {
        int f = tid + 256 * i;          // 0..1023
        int r = f >> 4, c8 = f & 15;
        int gr = row0 + r;
        uint4 vh = make_uint4(0, 0, 0, 0), vl = make_uint4(0, 0, 0, 0);
        if (gr < N_NODES) {
            vh = *(const uint4*)(hh + (long long)gr * D + c8 * 8);
            vl = *(const uint4*)(hl + (long long)gr * D + c8 * 8);
        }
        *(uint4*)&sH[r][c8 * 8] = vh;
        *(uint4*)&sL[r][c8 * 8] = vl;
    }
    __syncthreads();

    f32x4 acc[8];
#pragma unroll
    for (int t = 0; t < 8; ++t) acc[t] = (f32x4){0.f, 0.f, 0.f, 0.f};

    const int arow = wv * 16 + lc;
#pragma unroll
    for (int kk = 0; kk < 4; ++kk) {
        short8 ah = *(const short8*)&sH[arow][kk * 32 + qd * 8];
        short8 al = *(const short8*)&sL[arow][kk * 32 + qd * 8];
#pragma unroll
        for (int t = 0; t < 8; ++t) {
            const int woff = (t * 16 + lc) * D + kk * 32 + qd * 8;
            short8 bh = *(const short8*)(w1h + woff);
            short8 bl = *(const short8*)(w1l + woff);
            acc[t] = __builtin_amdgcn_mfma_f32_16x16x32_bf16(ah, bh, acc[t], 0, 0, 0);
            acc[t] = __builtin_amdgcn_mfma_f32_16x16x32_bf16(al, bh, acc[t], 0, 0, 0);
            acc[t] = __builtin_amdgcn_mfma_f32_16x16x32_bf16(ah, bl, acc[t], 0, 0, 0);
        }
    }

    // epilogue: +b1, write h1, per-column stats
    float psum[8], psq[8];
#pragma unroll
    for (int t = 0; t < 8; ++t) {
        int col = t * 16 + lc;
        float bb = b1[col];
        float s = 0.f, q = 0.f;
#pragma unroll
        for (int r = 0; r < 4; ++r) {
            int grow = row0 + wv * 16 + qd * 4 + r;
            if (grow < N_NODES) {
                float o = acc[t][r] + bb;
                h1[(long long)grow * D + col] = o;
                s += o;
                q += o * o;
            }
        }
        psum[t] = s; psq[t] = q;
    }
#pragma unroll
    for (int t = 0; t < 8; ++t) {
        float s = psum[t], q = psq[t];
        s += __shfl_xor(s, 16); s += __shfl_xor(s, 32);
        q += __shfl_xor(q, 16); q += __shfl_xor(q, 32);
        if (qd == 0) { sPart[0][wv][t * 16 + lc] = s; sPart[1][wv][t * 16 + lc] = q; }
    }
    __syncthreads();
    if (tid < 128) {
        float s = sPart[0][0][tid] + sPart[0][1][tid] + sPart[0][2][tid] + sPart[0][3][tid];
        float q = sPart[1][0][tid] + sPart[1][1][tid] + sPart[1][2][tid] + sPart[1][3][tid];
        atomicAdd(&stats[tid], s);
        atomicAdd(&stats[128 + tid], q);
    }
}

// ---------------------------------------------------------------------------
// K6: out = relu(bn(h1)) @ W2^T + b2  (MFMA split-bf16), in-place on d_out
// ---------------------------------------------------------------------------
__launch_bounds__(256)
__global__ void gemm2_mfma(float* __restrict__ h1out,
                           const unsigned short* __restrict__ w2h,
                           const unsigned short* __restrict__ w2l,
                           const float* __restrict__ b2, const float* __restrict__ stats,
                           const float* __restrict__ gamma, const float* __restrict__ beta) {
    __shared__ unsigned short sH[TM][136];
    __shared__ unsigned short sL[TM][136];
    __shared__ float sScale[128];
    __shared__ float sShift[128];
    const int tid = threadIdx.x;
    const int wv  = tid >> 6;
    const int ln  = tid & 63;
    const int lc  = ln & 15;
    const int qd  = ln >> 4;
    const int row0 = blockIdx.x * TM;

    if (tid < 128) {                      // fused BN finalize
        float mean = stats[tid] * (1.0f / N_NODES);
        float var  = fmaxf(stats[128 + tid] * (1.0f / N_NODES) - mean * mean, 0.0f);
        float s    = gamma[tid] * rsqrtf(var + BN_EPS);
        sScale[tid] = s;
        sShift[tid] = beta[tid] - mean * s;
    }
    __syncthreads();

    // stage: read h1 fp32, bn+relu, split to bf16 hi/lo
#pragma unroll
    for (int i = 0; i < 8; ++i) {
        int f = tid + 256 * i;            // 0..2047
        int r = f >> 5, c4 = f & 31;
        int gr = row0 + r;
        float4 v = make_float4(0.f, 0.f, 0.f, 0.f);
        if (gr < N_NODES) {
            v = *(const float4*)(h1out + (long long)gr * D + c4 * 4);
            float4 sc = *(const float4*)&sScale[c4 * 4];
            float4 sh = *(const float4*)&sShift[c4 * 4];
            v.x = fmaxf(0.f, fmaf(v.x, sc.x, sh.x));
            v.y = fmaxf(0.f, fmaf(v.y, sc.y, sh.y));
            v.z = fmaxf(0.f, fmaf(v.z, sc.z, sh.z));
            v.w = fmaxf(0.f, fmaf(v.w, sc.w, sh.w));
        }
        unsigned short h0 = bf_hi(v.x), h1b = bf_hi(v.y), h2 = bf_hi(v.z), h3 = bf_hi(v.w);
        unsigned short l0 = bf_hi(v.x - bf_val(h0)), l1 = bf_hi(v.y - bf_val(h1b));
        unsigned short l2 = bf_hi(v.z - bf_val(h2)), l3 = bf_hi(v.w - bf_val(h3));
        *(uint2*)&sH[r][c4 * 4] = make_uint2((unsigned)h0 | ((unsigned)h1b << 16),
                                             (unsigned)h2 | ((unsigned)h3 << 16));
        *(uint2*)&sL[r][c4 * 4] = make_uint2((unsigned)l0 | ((unsigned)l1 << 16),
                                             (unsigned)l2 | ((unsigned)l3 << 16));
    }
    __syncthreads();

    f32x4 acc[8];
#pragma unroll
    for (int t = 0; t < 8; ++t) acc[t] = (f32x4){0.f, 0.f, 0.f, 0.f};

    const int arow = wv * 16 + lc;
#pragma unroll
    for (int kk = 0; kk < 4; ++kk) {
        short8 ah = *(const short8*)&sH[arow][kk * 32 + qd * 8];
        short8 al = *(const short8*)&sL[arow][kk * 32 + qd * 8];
#pragma unroll
        for (int t = 0; t < 8; ++t) {
            const int woff = (t * 16 + lc) * D + kk * 32 + qd * 8;
            short8 bh = *(const short8*)(w2h + woff);
            short8 bl = *(const short8*)(w2l + woff);
            acc[t] = __builtin_amdgcn_mfma_f32_16x16x32_bf16(ah, bh, acc[t], 0, 0, 0);
            acc[t] = __builtin_amdgcn_mfma_f32_16x16x32_bf16(al, bh, acc[t], 0, 0, 0);
            acc[t] = __builtin_amdgcn_mfma_f32_16x16x32_bf16(ah, bl, acc[t], 0, 0, 0);
        }
    }

#pragma unroll
    for (int t = 0; t < 8; ++t) {
        int col = t * 16 + lc;
        float bb = b2[col];
#pragma unroll
        for (int r = 0; r < 4; ++r) {
            int grow = row0 + wv * 16 + qd * 4 + r;
            if (grow < N_NODES) {
                h1out[(long long)grow * D + col] = acc[t][r] + bb;
            }
        }
    }
}

// ---------------------------------------------------------------------------
extern "C" void kernel_launch(void* const* d_in, const int* in_sizes, int n_in,
                              void* d_out, int out_size, void* d_ws, size_t ws_size,
                              hipStream_t stream) {
    const float* x     = (const float*)d_in[0];
    const int*   ei    = (const int*)d_in[1];
    const float* eps_p = (const float*)d_in[2];
    const float* W1    = (const float*)d_in[3];
    const float* b1    = (const float*)d_in[4];
    const float* gamma = (const float*)d_in[5];
    const float* beta  = (const float*)d_in[6];
    const float* W2    = (const float*)d_in[7];
    const float* b2    = (const float*)d_in[8];

    // workspace layout (~64.4 MB, same footprint as R6)
    unsigned int* hh  = (unsigned int*)d_ws;                  // N*64 uints = hpre hi (bf16x2)
    unsigned int* hl  = hh + (long long)N_NODES * 64;         // hpre lo
    float* stats = (float*)(hl + (long long)N_NODES * 64);    // 512 floats
    int*   deg   = (int*)(stats + 512);                       // N ints (dead after scan -> W splits)
    int*   off   = deg + N_NODES;                             // N+1 ints
    int*   gcur  = off + N_NODES + 1;                         // NB ints
    int*   bsum  = gcur + 512;                                // NB ints
    int*   bbase = bsum + 512;                                // NB ints
    int*   adj   = bbase + 512;                               // 2E ints
    // W splits reuse the dead deg region (128 KB < 400 KB)
    unsigned short* w1h = (unsigned short*)deg;
    unsigned short* w1l = w1h + 16384;
    unsigned short* w2h = w1l + 16384;
    unsigned short* w2l = w2h + 16384;

    float* out   = (float*)d_out;                             // h1 scratch + final out
    __half* xh   = (__half*)d_out;                            // fp16 mirror: d_out[0:25.6MB]
    int2*  pairs = (int2*)(out + (long long)N_NODES * (D / 2)); // d_out[25.6:51.2MB]

    {   // K0: fp16 convert + zero stats/deg
        int grid = (N_NODES * (D / 4) + 255) / 256;
        convert_zero<<<grid, 256, 0, stream>>>(x, xh, (int*)stats);
    }
    {   // K1: degree histogram
        int grid = (EDGES / HB + 255) / 256;
        histo<<<grid, 256, 0, stream>>>(ei, deg);
    }
    {   // K2a-c: parallel exclusive scan
        bucket_sums<<<NB, 256, 0, stream>>>(deg, bsum);
        scan_bsums<<<1, 512, 0, stream>>>(bsum, bbase);
        scan_local<<<NB, 256, 0, stream>>>(deg, bbase, off, gcur);
    }
    {   // K2d: split W1/W2 -> bf16 hi/lo (into dead deg region)
        split_w<<<128, 256, 0, stream>>>(W1, W2, w1h, w1l, w2h, w2l);
    }
    {   // K3a: coarse-bucket partition
        int grid = (2 * EDGES + L1TILE - 1) / L1TILE;
        partition_pairs<<<grid, 256, 0, stream>>>(ei, gcur, pairs);
    }
    {   // K3b: exact CSR fill per bucket
        bucket_fill<<<NB, 256, 0, stream>>>(pairs, off, adj);
    }
    {   // K4: gather-aggregate -> split bf16 h_pre
        int grid = (N_NODES + 3) / 4;
        gather_aggr<<<grid, 256, 0, stream>>>(x, xh, adj, off, eps_p, hh, hl);
    }
    {   // K5: MFMA GEMM1 + BN stats (h1 -> d_out)
        int grid = (N_NODES + TM - 1) / TM;
        gemm1_mfma<<<grid, 256, 0, stream>>>((const unsigned short*)hh, (const unsigned short*)hl,
                                             w1h, w1l, b1, out, stats);
    }
    {   // K6: BN finalize + ReLU + MFMA GEMM2, in-place on d_out
        int grid = (N_NODES + TM - 1) / TM;
        gemm2_mfma<<<grid, 256, 0, stream>>>(out, w2h, w2l, b2, stats, gamma, beta);
    }
}

// Round 8
// 512.005 us; speedup vs baseline: 11.1679x; 1.2276x over previous
//
#include <hip/hip_runtime.h>
#include <hip/hip_fp16.h>

#define N_NODES 100000
#define EDGES   1600000
#define D       128
#define BN_EPS  1e-5f
#define TM      64                        // rows per GEMM block
#define NB      ((N_NODES + 255) >> 8)    // 391 coarse buckets (256 nodes each)
#define L1E     16                        // slots per thread in partition pass
#define L1TILE  (256 * L1E)               // 4096 slots per tile

typedef __attribute__((ext_vector_type(8))) short short8;
typedef __attribute__((ext_vector_type(4))) float f32x4;

__device__ __forceinline__ unsigned short bf_hi(float f) {
    unsigned u = __float_as_uint(f);
    unsigned t = u + 0x7FFF + ((u >> 16) & 1);
    return (unsigned short)(t >> 16);
}
__device__ __forceinline__ float bf_val(unsigned short h) {
    return __uint_as_float(((unsigned)h) << 16);
}

// ---------------------------------------------------------------------------
// K0: convert x -> fp16 mirror (in d_out scratch); zero stats(512f)+bsum(512i)
// ---------------------------------------------------------------------------
__global__ void convert_zero(const float* __restrict__ x, __half* __restrict__ xh,
                             int* __restrict__ zbase) {
    int gid = blockIdx.x * blockDim.x + threadIdx.x;
    if (gid < 1024) zbase[gid] = 0;
    const int n4 = N_NODES * (D / 4);
    if (gid < n4) {
        float4 v = ((const float4*)x)[gid];
        __half2 h0 = __float22half2_rn(make_float2(v.x, v.y));
        __half2 h1 = __float22half2_rn(make_float2(v.z, v.w));
        ((__half2*)xh)[(long long)gid * 2 + 0] = h0;
        ((__half2*)xh)[(long long)gid * 2 + 1] = h1;
    }
}

// ---------------------------------------------------------------------------
// K1: bucket-level histogram: LDS 391 counters/tile, 1 global atomic per
// (tile,bucket) -> 306K fire-and-forget atomics (vs 3.2M node-level before)
// ---------------------------------------------------------------------------
__launch_bounds__(256)
__global__ void bucket_count(const int* __restrict__ ei, int* __restrict__ bsum) {
    __shared__ int cnt[NB];
    const int tid = threadIdx.x;
    for (int i = tid; i < NB; i += 256) cnt[i] = 0;
    __syncthreads();
    const int t0 = blockIdx.x * L1TILE + tid;
#pragma unroll
    for (int j = 0; j < L1E; ++j) {
        int t = t0 + j * 256;
        if (t < 2 * EDGES) {
            int pt = (t < EDGES) ? t + EDGES : t - EDGES;
            atomicAdd(&cnt[ei[pt] >> 8], 1);
        }
    }
    __syncthreads();
    for (int i = tid; i < NB; i += 256) {
        int c = cnt[i];
        if (c) atomicAdd(&bsum[i], c);
    }
}

// ---------------------------------------------------------------------------
// K2: exclusive scan of 391 bucket sums -> bbase (NB+1), seed gcur
// ---------------------------------------------------------------------------
__global__ void scan_bsums(const int* __restrict__ bsum, int* __restrict__ bbase,
                           int* __restrict__ gcur) {
    __shared__ int s[512];
    const int t = threadIdx.x;
    s[t] = (t < NB) ? bsum[t] : 0;
    __syncthreads();
    for (int d = 1; d < 512; d <<= 1) {
        int u = (t >= d) ? s[t - d] : 0;
        __syncthreads();
        s[t] += u;
        __syncthreads();
    }
    if (t < NB) {
        int e = (t > 0) ? s[t - 1] : 0;
        bbase[t] = e;
        gcur[t] = e;
    }
    if (t == 0) bbase[NB] = 2 * EDGES;
}

// ---------------------------------------------------------------------------
// K2d: split W1/W2 into bf16 hi/lo
// ---------------------------------------------------------------------------
__global__ void split_w(const float* __restrict__ W1, const float* __restrict__ W2,
                        unsigned short* __restrict__ w1h, unsigned short* __restrict__ w1l,
                        unsigned short* __restrict__ w2h, unsigned short* __restrict__ w2l) {
    int i = blockIdx.x * blockDim.x + threadIdx.x;
    if (i < 16384) {
        float f = W1[i];
        unsigned short h = bf_hi(f);
        w1h[i] = h;
        w1l[i] = bf_hi(f - bf_val(h));
    } else if (i < 32768) {
        int j = i - 16384;
        float f = W2[j];
        unsigned short h = bf_hi(f);
        w2h[j] = h;
        w2l[j] = bf_hi(f - bf_val(h));
    }
}

// ---------------------------------------------------------------------------
// K3a: coarse-bucket partition (LDS ranks + 1 returning atomic per tile-bucket)
// ---------------------------------------------------------------------------
__launch_bounds__(256)
__global__ void partition_pairs(const int* __restrict__ ei, int* __restrict__ gcur,
                                int2* __restrict__ pairs) {
    __shared__ int cnt[NB];
    __shared__ int cbase[NB];
    const int tid = threadIdx.x;
    for (int i = tid; i < NB; i += 256) cnt[i] = 0;
    __syncthreads();

    int bb[L1E], rr[L1E], nd[L1E], vl[L1E];
    const int t0 = blockIdx.x * L1TILE + tid;
#pragma unroll
    for (int j = 0; j < L1E; ++j) {
        int t = t0 + j * 256;
        bb[j] = -1;
        if (t < 2 * EDGES) {
            vl[j] = ei[t];
            int pt = (t < EDGES) ? t + EDGES : t - EDGES;
            nd[j] = ei[pt];
            bb[j] = nd[j] >> 8;
            rr[j] = atomicAdd(&cnt[bb[j]], 1);
        }
    }
    __syncthreads();
    for (int i = tid; i < NB; i += 256) {
        int c = cnt[i];
        cbase[i] = c ? atomicAdd(&gcur[i], c) : 0;
    }
    __syncthreads();
#pragma unroll
    for (int j = 0; j < L1E; ++j) {
        if (bb[j] >= 0) pairs[cbase[bb[j]] + rr[j]] = make_int2(nd[j], vl[j]);
    }
}

// ---------------------------------------------------------------------------
// K3b: per-bucket: count node degrees in LDS, scan -> off[n], place adj
// ---------------------------------------------------------------------------
__launch_bounds__(256)
__global__ void bucket_fill(const int2* __restrict__ pairs, const int* __restrict__ bbase,
                            int* __restrict__ off, int* __restrict__ adj) {
    __shared__ int lc[256];
    __shared__ int cur[256];
    const int b   = blockIdx.x;
    const int n0  = b << 8;
    const int tid = threadIdx.x;
    const int s0 = bbase[b];
    const int s1 = bbase[b + 1];
    lc[tid] = 0;
    __syncthreads();
    // pass 1: node-degree count within bucket
    for (int i = s0 + tid; i < s1; i += 256)
        atomicAdd(&lc[pairs[i].x - n0], 1);
    __syncthreads();
    // exclusive scan
    int v = lc[tid];
    for (int d = 1; d < 256; d <<= 1) {
        int u = (tid >= d) ? lc[tid - d] : 0;
        __syncthreads();
        lc[tid] += u;
        __syncthreads();
    }
    int abs0 = s0 + lc[tid] - v;          // bucket base + exclusive scan
    cur[tid] = abs0;
    if (n0 + tid < N_NODES) off[n0 + tid] = abs0;
    if (b == 0 && tid == 0) off[N_NODES] = 2 * EDGES;
    __syncthreads();
    // pass 2: place
    for (int i = s0 + tid; i < s1; i += 256) {
        int2 p = pairs[i];
        int r = atomicAdd(&cur[p.x - n0], 1);
        adj[r] = p.y;
    }
}

// ---------------------------------------------------------------------------
// K4: gather-aggregate; emits h_pre as split bf16 (hi, lo) pair arrays
// ---------------------------------------------------------------------------
__launch_bounds__(256)
__global__ void gather_aggr(const float* __restrict__ x, const __half* __restrict__ xh,
                            const int* __restrict__ adj, const int* __restrict__ off,
                            const float* __restrict__ eps_p,
                            unsigned int* __restrict__ hh, unsigned int* __restrict__ hl) {
    int node = blockIdx.x * 4 + (threadIdx.x >> 6);
    int lane = threadIdx.x & 63;
    if (node >= N_NODES) return;
    int b = off[node];
    int e = off[node + 1];
    const __half2* xp = (const __half2*)xh;
    float ax = 0.f, ay = 0.f;
    int i = b;
    for (; i + 4 <= e; i += 4) {
        int n0 = adj[i], n1 = adj[i + 1], n2 = adj[i + 2], n3 = adj[i + 3];
        __half2 v0 = xp[(long long)n0 * 64 + lane];
        __half2 v1 = xp[(long long)n1 * 64 + lane];
        __half2 v2 = xp[(long long)n2 * 64 + lane];
        __half2 v3 = xp[(long long)n3 * 64 + lane];
        float2 f0 = __half22float2(v0);
        float2 f1 = __half22float2(v1);
        float2 f2 = __half22float2(v2);
        float2 f3 = __half22float2(v3);
        ax += (f0.x + f1.x) + (f2.x + f3.x);
        ay += (f0.y + f1.y) + (f2.y + f3.y);
    }
    for (; i < e; ++i) {
        __half2 v = xp[(long long)adj[i] * 64 + lane];
        float2 f = __half22float2(v);
        ax += f.x;
        ay += f.y;
    }
    float2 xs = ((const float2*)x)[(long long)node * 64 + lane];
    float sc = 2.0f + eps_p[0];
    float ox = fmaf(sc, xs.x, ax);
    float oy = fmaf(sc, xs.y, ay);
    unsigned short hx = bf_hi(ox), hy = bf_hi(oy);
    unsigned short lx = bf_hi(ox - bf_val(hx)), ly = bf_hi(oy - bf_val(hy));
    hh[(long long)node * 64 + lane] = (unsigned)hx | ((unsigned)hy << 16);
    hl[(long long)node * 64 + lane] = (unsigned)lx | ((unsigned)ly << 16);
}

// ---------------------------------------------------------------------------
// K5: h1 = h_pre @ W1^T + b1 (MFMA split-bf16, fp32-accurate) + BN stats
// ---------------------------------------------------------------------------
__launch_bounds__(256)
__global__ void gemm1_mfma(const unsigned short* __restrict__ hh,
                           const unsigned short* __restrict__ hl,
                           const unsigned short* __restrict__ w1h,
                           const unsigned short* __restrict__ w1l,
                           const float* __restrict__ b1, float* __restrict__ h1,
                           float* __restrict__ stats) {
    __shared__ unsigned short sH[TM][136];
    __shared__ unsigned short sL[TM][136];
    __shared__ float sPart[2][4][128];
    const int tid = threadIdx.x;
    const int wv  = tid >> 6;
    const int ln  = tid & 63;
    const int lc  = ln & 15;
    const int qd  = ln >> 4;
    const int row0 = blockIdx.x * TM;

#pragma unroll
    for (int i = 0; i < 4; ++i) {
        int f = tid + 256 * i;
        int r = f >> 4, c8 = f & 15;
        int gr = row0 + r;
        uint4 vh = make_uint4(0, 0, 0, 0), vl = make_uint4(0, 0, 0, 0);
        if (gr < N_NODES) {
            vh = *(const uint4*)(hh + (long long)gr * D + c8 * 8);
            vl = *(const uint4*)(hl + (long long)gr * D + c8 * 8);
        }
        *(uint4*)&sH[r][c8 * 8] = vh;
        *(uint4*)&sL[r][c8 * 8] = vl;
    }
    __syncthreads();

    f32x4 acc[8];
#pragma unroll
    for (int t = 0; t < 8; ++t) acc[t] = (f32x4){0.f, 0.f, 0.f, 0.f};

    const int arow = wv * 16 + lc;
#pragma unroll
    for (int kk = 0; kk < 4; ++kk) {
        short8 ah = *(const short8*)&sH[arow][kk * 32 + qd * 8];
        short8 al = *(const short8*)&sL[arow][kk * 32 + qd * 8];
#pragma unroll
        for (int t = 0; t < 8; ++t) {
            const int woff = (t * 16 + lc) * D + kk * 32 + qd * 8;
            short8 bh = *(const short8*)(w1h + woff);
            short8 bl = *(const short8*)(w1l + woff);
            acc[t] = __builtin_amdgcn_mfma_f32_16x16x32_bf16(ah, bh, acc[t], 0, 0, 0);
            acc[t] = __builtin_amdgcn_mfma_f32_16x16x32_bf16(al, bh, acc[t], 0, 0, 0);
            acc[t] = __builtin_amdgcn_mfma_f32_16x16x32_bf16(ah, bl, acc[t], 0, 0, 0);
        }
    }

    float psum[8], psq[8];
#pragma unroll
    for (int t = 0; t < 8; ++t) {
        int col = t * 16 + lc;
        float bb = b1[col];
        float s = 0.f, q = 0.f;
#pragma unroll
        for (int r = 0; r < 4; ++r) {
            int grow = row0 + wv * 16 + qd * 4 + r;
            if (grow < N_NODES) {
                float o = acc[t][r] + bb;
                h1[(long long)grow * D + col] = o;
                s += o;
                q += o * o;
            }
        }
        psum[t] = s; psq[t] = q;
    }
#pragma unroll
    for (int t = 0; t < 8; ++t) {
        float s = psum[t], q = psq[t];
        s += __shfl_xor(s, 16); s += __shfl_xor(s, 32);
        q += __shfl_xor(q, 16); q += __shfl_xor(q, 32);
        if (qd == 0) { sPart[0][wv][t * 16 + lc] = s; sPart[1][wv][t * 16 + lc] = q; }
    }
    __syncthreads();
    if (tid < 128) {
        float s = sPart[0][0][tid] + sPart[0][1][tid] + sPart[0][2][tid] + sPart[0][3][tid];
        float q = sPart[1][0][tid] + sPart[1][1][tid] + sPart[1][2][tid] + sPart[1][3][tid];
        atomicAdd(&stats[tid], s);
        atomicAdd(&stats[128 + tid], q);
    }
}

// ---------------------------------------------------------------------------
// K6: out = relu(bn(h1)) @ W2^T + b2  (MFMA split-bf16), in-place on d_out
// ---------------------------------------------------------------------------
__launch_bounds__(256)
__global__ void gemm2_mfma(float* __restrict__ h1out,
                           const unsigned short* __restrict__ w2h,
                           const unsigned short* __restrict__ w2l,
                           const float* __restrict__ b2, const float* __restrict__ stats,
                           const float* __restrict__ gamma, const float* __restrict__ beta) {
    __shared__ unsigned short sH[TM][136];
    __shared__ unsigned short sL[TM][136];
    __shared__ float sScale[128];
    __shared__ float sShift[128];
    const int tid = threadIdx.x;
    const int wv  = tid >> 6;
    const int ln  = tid & 63;
    const int lc  = ln & 15;
    const int qd  = ln >> 4;
    const int row0 = blockIdx.x * TM;

    if (tid < 128) {
        float mean = stats[tid] * (1.0f / N_NODES);
        float var  = fmaxf(stats[128 + tid] * (1.0f / N_NODES) - mean * mean, 0.0f);
        float s    = gamma[tid] * rsqrtf(var + BN_EPS);
        sScale[tid] = s;
        sShift[tid] = beta[tid] - mean * s;
    }
    __syncthreads();

#pragma unroll
    for (int i = 0; i < 8; ++i) {
        int f = tid + 256 * i;
        int r = f >> 5, c4 = f & 31;
        int gr = row0 + r;
        float4 v = make_float4(0.f, 0.f, 0.f, 0.f);
        if (gr < N_NODES) {
            v = *(const float4*)(h1out + (long long)gr * D + c4 * 4);
            float4 sc = *(const float4*)&sScale[c4 * 4];
            float4 sh = *(const float4*)&sShift[c4 * 4];
            v.x = fmaxf(0.f, fmaf(v.x, sc.x, sh.x));
            v.y = fmaxf(0.f, fmaf(v.y, sc.y, sh.y));
            v.z = fmaxf(0.f, fmaf(v.z, sc.z, sh.z));
            v.w = fmaxf(0.f, fmaf(v.w, sc.w, sh.w));
        }
        unsigned short h0 = bf_hi(v.x), h1b = bf_hi(v.y), h2 = bf_hi(v.z), h3 = bf_hi(v.w);
        unsigned short l0 = bf_hi(v.x - bf_val(h0)), l1 = bf_hi(v.y - bf_val(h1b));
        unsigned short l2 = bf_hi(v.z - bf_val(h2)), l3 = bf_hi(v.w - bf_val(h3));
        *(uint2*)&sH[r][c4 * 4] = make_uint2((unsigned)h0 | ((unsigned)h1b << 16),
                                             (unsigned)h2 | ((unsigned)h3 << 16));
        *(uint2*)&sL[r][c4 * 4] = make_uint2((unsigned)l0 | ((unsigned)l1 << 16),
                                             (unsigned)l2 | ((unsigned)l3 << 16));
    }
    __syncthreads();

    f32x4 acc[8];
#pragma unroll
    for (int t = 0; t < 8; ++t) acc[t] = (f32x4){0.f, 0.f, 0.f, 0.f};

    const int arow = wv * 16 + lc;
#pragma unroll
    for (int kk = 0; kk < 4; ++kk) {
        short8 ah = *(const short8*)&sH[arow][kk * 32 + qd * 8];
        short8 al = *(const short8*)&sL[arow][kk * 32 + qd * 8];
#pragma unroll
        for (int t = 0; t < 8; ++t) {
            const int woff = (t * 16 + lc) * D + kk * 32 + qd * 8;
            short8 bh = *(const short8*)(w2h + woff);
            short8 bl = *(const short8*)(w2l + woff);
            acc[t] = __builtin_amdgcn_mfma_f32_16x16x32_bf16(ah, bh, acc[t], 0, 0, 0);
            acc[t] = __builtin_amdgcn_mfma_f32_16x16x32_bf16(al, bh, acc[t], 0, 0, 0);
            acc[t] = __builtin_amdgcn_mfma_f32_16x16x32_bf16(ah, bl, acc[t], 0, 0, 0);
        }
    }

#pragma unroll
    for (int t = 0; t < 8; ++t) {
        int col = t * 16 + lc;
        float bb = b2[col];
#pragma unroll
        for (int r = 0; r < 4; ++r) {
            int grow = row0 + wv * 16 + qd * 4 + r;
            if (grow < N_NODES) {
                h1out[(long long)grow * D + col] = acc[t][r] + bb;
            }
        }
    }
}

// ---------------------------------------------------------------------------
extern "C" void kernel_launch(void* const* d_in, const int* in_sizes, int n_in,
                              void* d_out, int out_size, void* d_ws, size_t ws_size,
                              hipStream_t stream) {
    const float* x     = (const float*)d_in[0];
    const int*   ei    = (const int*)d_in[1];
    const float* eps_p = (const float*)d_in[2];
    const float* W1    = (const float*)d_in[3];
    const float* b1    = (const float*)d_in[4];
    const float* gamma = (const float*)d_in[5];
    const float* beta  = (const float*)d_in[6];
    const float* W2    = (const float*)d_in[7];
    const float* b2    = (const float*)d_in[8];

    // workspace layout (~64.3 MB)
    unsigned int* hh  = (unsigned int*)d_ws;                  // N*64 uints: hpre hi
    unsigned int* hl  = hh + (long long)N_NODES * 64;         // hpre lo
    float* stats = (float*)(hl + (long long)N_NODES * 64);    // 512 floats
    int*   bsum  = (int*)(stats + 512);                       // 512 ints (zeroed w/ stats)
    int*   bbase = bsum + 512;                                // NB+1 ints
    int*   gcur  = bbase + 512;                               // NB ints
    int*   off   = gcur + 512;                                // N+1 ints
    unsigned short* w1h = (unsigned short*)(off + N_NODES + 1);
    unsigned short* w1l = w1h + 16384;
    unsigned short* w2h = w1l + 16384;
    unsigned short* w2l = w2h + 16384;
    int*   adj   = (int*)(w2l + 16384);                       // 2E ints

    float* out   = (float*)d_out;                             // h1 scratch + final out
    __half* xh   = (__half*)d_out;                            // fp16 mirror: d_out[0:25.6MB]
    int2*  pairs = (int2*)(out + (long long)N_NODES * (D / 2)); // d_out[25.6:51.2MB]

    {   // K0: fp16 convert + zero stats/bsum
        int grid = (N_NODES * (D / 4) + 255) / 256;
        convert_zero<<<grid, 256, 0, stream>>>(x, xh, (int*)stats);
    }
    {   // K1: bucket histogram (LDS-aggregated, 306K global atomics)
        int grid = (2 * EDGES + L1TILE - 1) / L1TILE;
        bucket_count<<<grid, 256, 0, stream>>>(ei, bsum);
    }
    {   // K2: scan bucket sums -> bbase, gcur
        scan_bsums<<<1, 512, 0, stream>>>(bsum, bbase, gcur);
    }
    {   // K2d: split W1/W2 -> bf16 hi/lo
        split_w<<<128, 256, 0, stream>>>(W1, W2, w1h, w1l, w2h, w2l);
    }
    {   // K3a: coarse-bucket partition
        int grid = (2 * EDGES + L1TILE - 1) / L1TILE;
        partition_pairs<<<grid, 256, 0, stream>>>(ei, gcur, pairs);
    }
    {   // K3b: per-bucket count+scan+place -> off, adj
        bucket_fill<<<NB, 256, 0, stream>>>(pairs, bbase, off, adj);
    }
    {   // K4: gather-aggregate -> split bf16 h_pre
        int grid = (N_NODES + 3) / 4;
        gather_aggr<<<grid, 256, 0, stream>>>(x, xh, adj, off, eps_p, hh, hl);
    }
    {   // K5: MFMA GEMM1 + BN stats (h1 -> d_out)
        int grid = (N_NODES + TM - 1) / TM;
        gemm1_mfma<<<grid, 256, 0, stream>>>((const unsigned short*)hh, (const unsigned short*)hl,
                                             w1h, w1l, b1, out, stats);
    }
    {   // K6: BN finalize + ReLU + MFMA GEMM2, in-place on d_out
        int grid = (N_NODES + TM - 1) / TM;
        gemm2_mfma<<<grid, 256, 0, stream>>>(out, w2h, w2l, b2, stats, gamma, beta);
    }
}